// Round 16
// baseline (1232.405 us; speedup 1.0000x reference)
//
// NeRTModel_60997125538302 — round 16: hybrid MFMA score phase inside fused pooling.
// r15 null: LDS 79.9KB did NOT give 2 blk/CU (Occ stuck 22.5%); fused pooling at same
// 8 waves/CU as r13 is 1.44x slower -> the 640-row serial score loop + 512-wide barrier
// convoy is the cost. Fix: score phase = 40 MFMAs reading A/B fragments DIRECTLY from
// the existing stride-404 qs/kss LDS with per-kg masking (kg=2 hi-half zeroed masks both
// cross-head and pad garbage; 8B-aligned short4v loads). r12 proved the math; r13 proved
// the tok-LDS pooling. Everything else identical to r15.

#include <hip/hip_runtime.h>
#include <hip/hip_bf16.h>
#include <cstdint>
#include <cstddef>

typedef unsigned short u16;
typedef __attribute__((ext_vector_type(8))) short short8v;
typedef __attribute__((ext_vector_type(4))) short short4v;
typedef __attribute__((ext_vector_type(4))) float f32x4;
typedef __attribute__((ext_vector_type(4))) int i32x4;

#define MFMA16 __builtin_amdgcn_mfma_f32_16x16x32_bf16
#define MFMAI8 __builtin_amdgcn_mfma_i32_16x16x64_i8

__device__ __forceinline__ float bf2f(u16 u){
  union { unsigned int i; float f; } v; v.i = ((unsigned int)u) << 16; return v.f;
}
__device__ __forceinline__ u16 f2bf(float f){
  union { float f; unsigned int u; } v; v.f = f;
  unsigned int r = v.u + 0x7FFFu + ((v.u >> 16) & 1u);
  return (u16)(r >> 16);
}
__device__ __forceinline__ short8v szero(){
  short8v z;
  #pragma unroll
  for (int i = 0; i < 8; i++) z[i] = 0;
  return z;
}
__device__ __forceinline__ float sigm(float x){ return 1.0f/(1.0f + __expf(-x)); }
__device__ __forceinline__ float tanh_u(float x){
  float e = __expf(2.f*x);              // overflow -> inf -> tanh -> 1 (no NaN)
  return 1.f - 2.f/(e + 1.f);
}
// LDS-visibility-only barrier: does NOT drain vmcnt.
__device__ __forceinline__ void lds_barrier(){
  asm volatile("s_waitcnt lgkmcnt(0)" ::: "memory");
  __builtin_amdgcn_s_barrier();
  __builtin_amdgcn_sched_barrier(0);
}

// ---------------- K0: convert non-recurrent weights f32 -> bf16; fuse LSTM biases ----------------
__global__ void k0_cvt(const float* __restrict__ wq, const float* __restrict__ wk,
                       const float* __restrict__ wihf, const float* __restrict__ wihb,
                       const float* __restrict__ bihf, const float* __restrict__ bhhf,
                       const float* __restrict__ bihb, const float* __restrict__ bhhb,
                       u16* __restrict__ wqb, u16* __restrict__ wkb,
                       u16* __restrict__ wihfb, u16* __restrict__ wihbb,
                       float* __restrict__ bgf, float* __restrict__ bgb){
  int i = blockIdx.x*256 + threadIdx.x;
  if (i < 160000){ wqb[i] = f2bf(wq[i]); wkb[i] = f2bf(wk[i]); }
  if (i < 320000){ wihfb[i] = f2bf(wihf[i]); wihbb[i] = f2bf(wihb[i]); }
  if (i < 800){ bgf[i] = bihf[i] + bhhf[i]; bgb[i] = bihb[i] + bhhb[i]; }
}

// ---------------- K0b: row-quantize W_hh -> i8 [4 gate][208 row][256 k] + scales ----------------
__global__ void k0b_quant(const float* __restrict__ whhf, const float* __restrict__ whhb,
                          signed char* __restrict__ w8f, signed char* __restrict__ w8b,
                          float* __restrict__ sclf, float* __restrict__ sclb){
  const int tid = threadIdx.x, lane = tid & 63, wv = tid >> 6;
  const int widx = blockIdx.x*4 + wv;              // 0..1663
  if (widx < 1600){
    int dir = widx / 800, g = widx - dir*800;
    const float* src = (dir ? whhb : whhf) + (size_t)g*200;
    float mx = 0.f;
    for (int j = lane; j < 200; j += 64) mx = fmaxf(mx, fabsf(src[j]));
    #pragma unroll
    for (int m = 32; m > 0; m >>= 1) mx = fmaxf(mx, __shfl_xor(mx, m, 64));
    float inv = (mx > 0.f) ? 127.f/mx : 0.f;
    int gt = g / 200, hl = g - gt*200;
    signed char* dst = (dir ? w8b : w8f) + (size_t)(gt*208 + hl)*256;
    int e0 = lane*4;
    unsigned int pack = 0u;
    if (e0 < 200){
      #pragma unroll
      for (int r = 0; r < 4; r++){
        int qv = __float2int_rn(src[e0+r]*inv);
        pack |= ((unsigned int)(qv & 255)) << (8*r);
      }
    }
    ((unsigned int*)dst)[lane] = pack;               // lanes 50..63 zero the k-pad
    if (lane == 0) (dir ? sclb : sclf)[g] = mx / 16129.f;   // mx / 127^2
  } else {
    int pr = widx - 1600;                            // 64 pad rows
    int dir = pr >> 5, rem = pr & 31, gt = rem >> 3, hl = 200 + (rem & 7);
    signed char* dst = (dir ? w8b : w8f) + (size_t)(gt*208 + hl)*256;
    ((unsigned int*)dst)[lane] = 0u;
  }
}

// ---------------- K3: xW = x @ W_ih^T + (b_ih+b_hh), layout [t][b32][hu][gt] bf16 ----------------
__launch_bounds__(512)
__global__ void k3_xw(const float* __restrict__ x1, const int* __restrict__ seq,
                      const u16* __restrict__ wihfb, const u16* __restrict__ wihbb,
                      const float* __restrict__ bgf, const float* __restrict__ bgb,
                      u16* __restrict__ xWf, u16* __restrict__ xWb){
  __shared__ u16 xf[12800];
  __shared__ u16 xb[12800];
  const int tid = threadIdx.x;
  const int t = blockIdx.x;
  for (int i = tid; i < 3200; i += 512){
    int b = i / 100, e4 = i - b*100;
    f32x4 vf = *(const f32x4*)&x1[((size_t)b*256 + t)*400 + e4*4];
    int rb = seq[b] - 1 - t; if (rb < 0) rb = 0;     // clip(L-1-t, 0, T-1)
    f32x4 vb = *(const f32x4*)&x1[((size_t)b*256 + rb)*400 + e4*4];
    short4v sf, sb;
    #pragma unroll
    for (int r = 0; r < 4; r++){ sf[r] = f2bf(vf[r]); sb[r] = f2bf(vb[r]); }
    ((short4v*)xf)[i] = sf;
    ((short4v*)xb)[i] = sb;
  }
  __syncthreads();
  const int lane = tid & 63, wv = tid >> 6;
  const int dir = wv >> 2, wl = wv & 3;
  const u16* xs = dir ? xb : xf;
  const u16* W  = dir ? wihbb : wihfb;
  const float* bg = dir ? bgb : bgf;
  u16* xW = dir ? xWb : xWf;
  const int q = lane & 15, kg = lane >> 4;
  short8v A[2][13];
  #pragma unroll
  for (int mt = 0; mt < 2; mt++)
    #pragma unroll
    for (int ksi = 0; ksi < 13; ksi++){
      int e0 = ksi*32 + kg*8;
      A[mt][ksi] = (e0 < 400) ? *(const short8v*)&xs[(mt*16 + q)*400 + e0] : szero();
    }
  for (int nt = wl; nt < 50; nt += 4){
    int g = nt*16 + q;                       // gate row 0..799
    float bv = bg[g];
    f32x4 acc0, acc1;
    acc0[0]=bv; acc0[1]=bv; acc0[2]=bv; acc0[3]=bv; acc1 = acc0;
    const u16* wrow = W + (size_t)g*400;
    #pragma unroll
    for (int ksi = 0; ksi < 13; ksi++){
      int e0 = ksi*32 + kg*8;
      short8v bf = (e0 < 400) ? *(const short8v*)&wrow[e0] : szero();
      acc0 = MFMA16(A[0][ksi], bf, acc0, 0,0,0);
      acc1 = MFMA16(A[1][ksi], bf, acc1, 0,0,0);
    }
    int gt = g / 200, hu = g - gt*200;
    #pragma unroll
    for (int r = 0; r < 4; r++){
      int bl = kg*4 + r;                     // D rows = batch rows
      xW[(((size_t)t*32 +      bl)*200 + hu)*4 + gt] = f2bf(acc0[r]);
      xW[(((size_t)t*32 + 16 + bl)*200 + hu)*4 + gt] = f2bf(acc1[r]);
    }
  }
}

// ---------------- K41: FUSED LSTM (blocks 0-15, 37KB LDS) + pooling (blocks 16+). ----------------
__device__ __forceinline__ void store_gate_f32(int p, const i32x4& acc, int q, int kg,
                                               float* gates, const float* scl_s){
  int gt = p/13, nt = p - gt*13;
  int hu0 = nt*16 + kg*4;
  if (hu0 < 200 && q < 4){
    const f32x4 s4 = *(const f32x4*)&scl_s[gt*200 + hu0];
    #pragma unroll
    for (int r = 0; r < 4; r++)
      gates[q*804 + (hu0+r)*4 + gt] = (float)acc[r]*s4[r];
  }
}

__launch_bounds__(512)
__global__ void k41_fused(const u16* __restrict__ xWf, const u16* __restrict__ xWb,
                          const signed char* __restrict__ w8f, const signed char* __restrict__ w8b,
                          const float* __restrict__ sclf, const float* __restrict__ sclb,
                          const int* __restrict__ seq, float* __restrict__ h_ws,
                          const float* __restrict__ x2,
                          const u16* __restrict__ wqb, const float* __restrict__ bq,
                          const u16* __restrict__ wkb, const float* __restrict__ bk,
                          float* __restrict__ pooled){
  __shared__ __align__(16) char smem[79616];
  const int tid = threadIdx.x;
  const int bid = blockIdx.x;
  const int lane = tid & 63, wv = tid >> 6;
  const int q = lane & 15, kg = lane >> 4;

  if (bid < 16){
    // ============ LSTM path: 6 reg pairs + 4 LDS pool pairs; LDS 37KB ============
    __builtin_amdgcn_s_setprio(2);                     // protect recurrence critical path
    signed char* h8   = (signed char*)smem;            // 4,608
    float* gates      = (float*)(smem + 4608);         // 12,864 -> 17,472
    i32x4* pool       = (i32x4*)(smem + 17472);        // 16,384 -> 33,856
    float* scl_s      = (float*)(smem + 33856);        // 3,200 -> 37,056
    int* Ls           = (int*)(smem + 37056);          // 16 -> 37,072
    const int dir = bid >> 3, grp = bid & 7;
    const u16* xWd = dir ? xWb : xWf;
    const signed char* w8 = dir ? w8b : w8f;
    const float* scl = dir ? sclb : sclf;
    if (tid < 4) Ls[tid] = seq[grp*4 + tid];
    for (int i = tid; i < 1152; i += 512) ((int*)h8)[i] = 0;
    for (int i = tid; i < 800; i += 512) scl_s[i] = scl[i];
    for (int idx = tid; idx < 1024; idx += 512){
      int s = idx >> 8, rem = idx & 255;
      int ksi = rem >> 6, l = rem & 63;
      int qq = l & 15, kk = l >> 4;
      pool[idx] = *(const i32x4*)&w8[(size_t)(3*208 + (9+s)*16 + qq)*256 + ksi*64 + kk*16];
    }
    i32x4 Wr[6][4];
    #pragma unroll
    for (int j = 0; j < 6; j++){
      int p = wv + 8*j, gt = p/13, nt = p - gt*13;
      #pragma unroll
      for (int ksi = 0; ksi < 4; ksi++)
        Wr[j][ksi] = *(const i32x4*)&w8[(size_t)(gt*208 + nt*16 + q)*256 + ksi*64 + kg*16];
    }
    float cst0 = 0.f, cst1 = 0.f;
    const int c0 = tid,        b0c = c0/200, hu0c = c0 - b0c*200;
    const int qd1 = tid + 512;
    const int b1c = qd1/200,   hu1c = qd1 - b1c*200;
    const int xoff0 = ((grp*4 + b0c)*200 + hu0c)*4;
    const int xoff1 = ((grp*4 + b1c)*200 + hu1c)*4;
    short4v xc0 = *(const short4v*)&xWd[xoff0];
    short4v xc1 = {0,0,0,0};
    if (tid < 288) xc1 = *(const short4v*)&xWd[xoff1];
    __syncthreads();
    #pragma unroll 1
    for (int t = 0; t < 256; t++){
      int tn = (t + 1 < 256) ? t + 1 : 255;
      const u16* xwn = xWd + (size_t)tn*25600;
      short4v xn0 = *(const short4v*)&xwn[xoff0];
      short4v xn1 = {0,0,0,0};
      if (tid < 288) xn1 = *(const short4v*)&xwn[xoff1];
      i32x4 bh[4];
      #pragma unroll
      for (int ksi = 0; ksi < 4; ksi++)
        bh[ksi] = *(const i32x4*)&h8[q*288 + ksi*64 + kg*16];
      #pragma unroll
      for (int j = 0; j < 6; j++){
        i32x4 acc = {0,0,0,0};
        #pragma unroll
        for (int ksi = 0; ksi < 4; ksi++)
          acc = MFMAI8(Wr[j][ksi], bh[ksi], acc, 0,0,0);
        store_gate_f32(wv + 8*j, acc, q, kg, gates, scl_s);
      }
      if (wv < 4){                                   // pool pair p = 48+wv
        i32x4 acc = {0,0,0,0};
        #pragma unroll
        for (int ksi = 0; ksi < 4; ksi++)
          acc = MFMAI8(pool[(wv*4 + ksi)*64 + lane], bh[ksi], acc, 0,0,0);
        store_gate_f32(48 + wv, acc, q, kg, gates, scl_s);
      }
      lds_barrier();
      {
        const f32x4 g4 = *(const f32x4*)&gates[b0c*804 + hu0c*4];
        float gi = g4[0] + bf2f((u16)xc0[0]);
        float gf = g4[1] + bf2f((u16)xc0[1]);
        float gg = g4[2] + bf2f((u16)xc0[2]);
        float go = g4[3] + bf2f((u16)xc0[3]);
        float c = sigm(gf)*cst0 + sigm(gi)*tanh_u(gg);
        cst0 = c;
        float hv = sigm(go)*tanh_u(c);
        h8[b0c*288 + hu0c] = (signed char)__float2int_rn(hv*127.f);
        int gb = grp*4 + b0c;
        if (dir == 0){
          h_ws[((size_t)gb*256 + t)*400 + hu0c] = hv;
        } else {
          int tp = Ls[b0c] - 1 - t;
          if (tp >= 0) h_ws[((size_t)gb*256 + tp)*400 + 200 + hu0c] = hv;
        }
      }
      if (tid < 288){
        const f32x4 g4 = *(const f32x4*)&gates[b1c*804 + hu1c*4];
        float gi = g4[0] + bf2f((u16)xc1[0]);
        float gf = g4[1] + bf2f((u16)xc1[1]);
        float gg = g4[2] + bf2f((u16)xc1[2]);
        float go = g4[3] + bf2f((u16)xc1[3]);
        float c = sigm(gf)*cst1 + sigm(gi)*tanh_u(gg);
        cst1 = c;
        float hv = sigm(go)*tanh_u(c);
        h8[b1c*288 + hu1c] = (signed char)__float2int_rn(hv*127.f);
        int gb = grp*4 + b1c;
        if (dir == 0){
          h_ws[((size_t)gb*256 + t)*400 + hu1c] = hv;
        } else {
          int tp = Ls[b1c] - 1 - t;
          if (tp >= 0) h_ws[((size_t)gb*256 + tp)*400 + 200 + hu1c] = hv;
        }
      }
      lds_barrier();
      xc0 = xn0; xc1 = xn1;
    }
  } else {
    // ============ pooling path: proj MFMA -> MFMA scores (404-layout frags) -> pool ============
    u16* tok0  = (u16*)smem;                 // 25,600
    u16* qsb   = (u16*)(smem + 25600);       // 25,856 -> 51,456
    u16* ksb   = (u16*)(smem + 51456);       // 25,856 -> 77,312
    float* msum= (float*)(smem + 77312);     // 2,048 -> 79,360
    float* tval= (float*)(smem + 79360);     // 128
    float* attw= (float*)(smem + 79488);     // 128 -> 79,616
    const int kb = bid - 16;
    const size_t n0 = (size_t)kb * 2;
    const float* src = x2 + n0*6400;
    msum[tid & 511] = 0.f;
    for (int i = tid; i < 3200; i += 512){
      f32x4 v = *(const f32x4*)&src[(size_t)i*4];
      short4v s; s[0]=f2bf(v[0]); s[1]=f2bf(v[1]); s[2]=f2bf(v[2]); s[3]=f2bf(v[3]);
      int j = i / 1600, r = i - j*1600;
      ((short4v*)(tok0 + j*6400))[r] = s;
    }
    __syncthreads();
    {
      const int proj = wv >> 2;              // waves 0-3: q, 4-7: k
      const int jn   = (wv >> 1) & 1;
      const int half = wv & 1;
      const int ntbase = half ? 13 : 0;
      const int ntcnt  = half ? 12 : 13;
      const u16* W    = proj ? wkb : wqb;
      const float* bias = proj ? bk : bq;
      const u16* tokj = tok0 + jn*6400;
      u16* dst = (proj ? ksb : qsb) + jn*6464;
      short8v A[13];
      #pragma unroll
      for (int ksi = 0; ksi < 13; ksi++){
        int e0 = ksi*32 + kg*8;
        A[ksi] = (e0 < 400) ? *(const short8v*)&tokj[q*400 + e0] : szero();
      }
      for (int ti = 0; ti < ntcnt; ti++){
        int col = (ntbase + ti)*16 + q;
        float bv = bias[col];
        f32x4 acc;
        acc[0]=bv; acc[1]=bv; acc[2]=bv; acc[3]=bv;
        const u16* wrow = W + (size_t)col*400;
        #pragma unroll
        for (int ksi = 0; ksi < 13; ksi++){
          int e0 = ksi*32 + kg*8;
          short8v bf = (e0 < 400) ? *(const short8v*)&wrow[e0] : szero();
          acc = MFMA16(A[ksi], bf, acc, 0, 0, 0);
        }
        #pragma unroll
        for (int r = 0; r < 4; r++)          // D: row=(l>>4)*4+r, col=l&15
          dst[(kg*4+r)*404 + col] = f2bf(acc[r]);
      }
    }
    __syncthreads();
    // MFMA scores: 40 tasks (nj,hh) over 8 waves, 5 each. A/B frags from 404 layout;
    // kg=2 hi-half zeroed (masks cross-head + pad), kg=3 all-zero. K=32 covers d<20.
    for (int ti = 0; ti < 5; ti++){
      int tsk = wv*5 + ti;
      int nj = tsk / 20, hh = tsk - nj*20;
      const u16* qrow = qsb + nj*6464 + q*404 + hh*20 + kg*8;
      const u16* krow = ksb + nj*6464 + q*404 + hh*20 + kg*8;
      short8v qa = szero(), ka = szero();
      if (kg < 3){
        short4v ql = *(const short4v*)qrow;
        short4v kl = *(const short4v*)krow;
        qa[0]=ql[0]; qa[1]=ql[1]; qa[2]=ql[2]; qa[3]=ql[3];
        ka[0]=kl[0]; ka[1]=kl[1]; ka[2]=kl[2]; ka[3]=kl[3];
        if (kg < 2){
          short4v qh2 = *(const short4v*)(qrow + 4);
          short4v kh2 = *(const short4v*)(krow + 4);
          qa[4]=qh2[0]; qa[5]=qh2[1]; qa[6]=qh2[2]; qa[7]=qh2[3];
          ka[4]=kh2[0]; ka[5]=kh2[1]; ka[6]=kh2[2]; ka[7]=kh2[3];
        }
      }
      f32x4 acc; acc[0]=0.f; acc[1]=0.f; acc[2]=0.f; acc[3]=0.f;
      acc = MFMA16(qa, ka, acc, 0, 0, 0);     // D[sq=kg*4+r][sk=q]
      #pragma unroll
      for (int r = 0; r < 4; r++){
        float s = acc[r] * 0.22360679775f;    // 1/sqrt(20)
        float mx = s;
        #pragma unroll
        for (int m = 1; m < 16; m <<= 1) mx = fmaxf(mx, __shfl_xor(mx, m, 64));
        float e = __expf(s - mx);
        float sum = e;
        #pragma unroll
        for (int m = 1; m < 16; m <<= 1) sum += __shfl_xor(sum, m, 64);
        float p = e/sum * 0.05f;              // fold 1/20 head-mean
        atomicAdd(&msum[nj*256 + (kg*4 + r)*16 + q], p);
      }
    }
    __syncthreads();
    if (tid < 32){
      int j = tid >> 4, sq = tid & 15;
      float s = 0.f;
      #pragma unroll
      for (int sk = 0; sk < 16; sk++) s += msum[j*256 + sq*16+sk];
      tval[j*16 + sq] = s * 0.0625f;
    }
    __syncthreads();
    if (tid < 2){
      float mx = -1e30f;
      for (int i = 0; i < 16; i++) mx = fmaxf(mx, tval[tid*16+i]);
      float sum = 0.f; float ev[16];
      for (int i = 0; i < 16; i++){ ev[i] = __expf(tval[tid*16+i]-mx); sum += ev[i]; }
      float inv = 1.f/sum;
      for (int i = 0; i < 16; i++) attw[tid*16+i] = ev[i]*inv;
    }
    __syncthreads();
    for (int e = tid; e < 800; e += 512){
      int j = e / 400, c = e - j*400;
      float acc = 0.f;
      #pragma unroll
      for (int s = 0; s < 16; s++) acc += attw[j*16+s]*bf2f(tok0[j*6400 + s*400 + c]);
      pooled[(n0+j)*400 + c] = acc;
    }
  }
}

// ---------------- K2: x2p = pooled @ w_mlp_mha^T + b (f32 VALU) ----------------
__global__ void k2_x2p(const float* __restrict__ pooled, const float* __restrict__ wmha,
                       const float* __restrict__ bmha, float* __restrict__ x2p){
  __shared__ float rows[3200];
  const int tid = threadIdx.x;
  const size_t n0 = (size_t)blockIdx.x*8;
  for (int i = tid; i < 3200; i += 256) rows[i] = pooled[n0*400 + i];
  __syncthreads();
  for (int j = tid; j < 400; j += 256){
    float bv = bmha[j];
    float acc[8];
    #pragma unroll
    for (int r = 0; r < 8; r++) acc[r] = bv;
    const float* wr = wmha + (size_t)j*400;
    for (int e = 0; e < 400; e += 4){
      const f32x4 w4 = *(const f32x4*)&wr[e];
      #pragma unroll
      for (int r = 0; r < 8; r++){
        const f32x4 x4 = *(const f32x4*)&rows[r*400 + e];
        acc[r] += x4[0]*w4[0] + x4[1]*w4[1] + x4[2]*w4[2] + x4[3]*w4[3];
      }
    }
    #pragma unroll
    for (int r = 0; r < 8; r++) x2p[(n0+r)*400 + j] = acc[r];
  }
}

// ---------------- K4b: fill bwd rows t>=L AND compute a[b][t] + per-b max ----------------
__global__ void k4b_fill(const int* __restrict__ seq, float* __restrict__ h_ws,
                         const float* __restrict__ wattn,
                         float* __restrict__ a_ws, float* __restrict__ amax_ws){
  __shared__ float a_lds[256];
  const int b = blockIdx.x;
  const int tid = threadIdx.x;
  const int lane = tid & 63, wv = tid >> 6;
  const int L = seq[b];
  const int cnt = (256 - L)*200;
  const float* srcf = h_ws + ((size_t)b*256 + (L-1))*400 + 200;
  for (int i = tid; i < cnt; i += 256){
    int tt = L + i/200, cc = i - (i/200)*200;
    h_ws[((size_t)b*256 + tt)*400 + 200 + cc] = srcf[cc];
  }
  __syncthreads();
  for (int row = wv*64; row < wv*64 + 64; row++){
    float s = 0.f;
    for (int j = lane; j < 400; j += 64)
      s += h_ws[((size_t)b*256 + row)*400 + j] * wattn[j];
    #pragma unroll
    for (int m = 32; m > 0; m >>= 1) s += __shfl_xor(s, m, 64);
    if (lane == 0) a_lds[row] = s;
  }
  __syncthreads();
  a_ws[b*256 + tid] = a_lds[tid];
  if (tid < 64){
    float m = fmaxf(fmaxf(a_lds[tid], a_lds[tid+64]), fmaxf(a_lds[tid+128], a_lds[tid+192]));
    #pragma unroll
    for (int mm = 32; mm > 0; mm >>= 1) m = fmaxf(m, __shfl_xor(m, mm, 64));
    if (tid == 0) amax_ws[b] = m;
  }
}

// ---------------- K5: causal attention as exact cumsum (const per-b max). grid 256. ----------------
__launch_bounds__(256)
__global__ void k5_attn(const float* __restrict__ h_ws, const float* __restrict__ a_ws,
                        const float* __restrict__ amax_ws, float* __restrict__ x1_att){
  __shared__ float tile[256*52];       // [t][col-chunk 50, pad 52], in-place h -> out
  __shared__ float wl[256];
  const int tid = threadIdx.x;
  const int b = blockIdx.x >> 3, ch = blockIdx.x & 7;
  const int c0 = ch*50;
  wl[tid] = __expf(a_ws[b*256 + tid] - amax_ws[b]);
  for (int i = tid; i < 12800; i += 256){
    int r = i / 50, c = i - r*50;
    tile[r*52 + c] = h_ws[((size_t)b*256 + r)*400 + c0 + c];
  }
  __syncthreads();
  if (tid < 50){
    float den = 0.f, num = 0.f;
    #pragma unroll 4
    for (int t = 0; t < 256; t++){
      float w = wl[t];
      den += w;
      num += w * tile[t*52 + tid];
      tile[t*52 + tid] = num/den;
    }
  }
  __syncthreads();
  for (int i = tid; i < 12800; i += 256){
    int r = i / 50, c = i - r*50;
    x1_att[((size_t)b*256 + r)*400 + c0 + c] = tile[r*52 + c];
  }
}

// ---------------- K6: out = [x1_att ; x2p] @ w_mlp^T + b, masked, f32 ----------------
__global__ void k6_out(const float* __restrict__ x1_att, const float* __restrict__ x2p,
                       const float* __restrict__ wmlp, const float* __restrict__ bmlp,
                       const int* __restrict__ seq, float* __restrict__ out){
  __shared__ float rows[8*800];
  const int tid = threadIdx.x;
  const size_t n0 = (size_t)blockIdx.x*8;
  const int b = (int)(n0 >> 8), t0 = (int)(n0 & 255);
  const int L = seq[b];
  for (int i = tid; i < 3200; i += 256){
    int r = i / 400, e = i - r*400;
    rows[r*800 + e]       = x1_att[(n0 + r)*400 + e];
    rows[r*800 + 400 + e] = x2p  [(n0 + r)*400 + e];
  }
  __syncthreads();
  for (int e = tid; e < 400; e += 256){
    float bv = bmlp[e];
    float acc[8];
    #pragma unroll
    for (int r = 0; r < 8; r++) acc[r] = bv;
    const float* wr = wmlp + (size_t)e*800;
    for (int j = 0; j < 800; j += 4){
      const f32x4 w4 = *(const f32x4*)&wr[j];
      #pragma unroll
      for (int r = 0; r < 8; r++){
        const f32x4 x4 = *(const f32x4*)&rows[r*800 + j];
        acc[r] += x4[0]*w4[0] + x4[1]*w4[1] + x4[2]*w4[2] + x4[3]*w4[3];
      }
    }
    #pragma unroll
    for (int r = 0; r < 8; r++){
      float v = (t0 + r < L) ? acc[r] : 0.f;
      out[(n0 + r)*400 + e] = v;
    }
  }
}

extern "C" void kernel_launch(void* const* d_in, const int* in_sizes, int n_in,
                              void* d_out, int out_size, void* d_ws, size_t ws_size,
                              hipStream_t stream){
  const float* x1   = (const float*)d_in[0];
  const float* x2   = (const float*)d_in[1];
  // d_in[2] = cate: unused by the reference
  const int*   seq  = (const int*)d_in[3];
  const float* wihf = (const float*)d_in[4];
  const float* whhf = (const float*)d_in[5];
  const float* bihf = (const float*)d_in[6];
  const float* bhhf = (const float*)d_in[7];
  const float* wihb = (const float*)d_in[8];
  const float* whhb = (const float*)d_in[9];
  const float* bihb = (const float*)d_in[10];
  const float* bhhb = (const float*)d_in[11];
  const float* wq   = (const float*)d_in[12];
  const float* bq   = (const float*)d_in[13];
  const float* wk   = (const float*)d_in[14];
  const float* bk   = (const float*)d_in[15];
  const float* wmha = (const float*)d_in[16];
  const float* bmha = (const float*)d_in[17];
  const float* wattn= (const float*)d_in[18];
  // d_in[19] = b_attn: cancels in softmax
  const float* wmlp = (const float*)d_in[20];
  const float* bmlp = (const float*)d_in[21];
  float* out = (float*)d_out;

  char* ws = (char*)d_ws;
  u16*  wqb    = (u16*)(ws + 0);              // 320,000 B
  u16*  wkb    = (u16*)(ws + 320000);         // 320,000
  u16*  wihfb  = (u16*)(ws + 640000);         // 640,000
  u16*  wihbb  = (u16*)(ws + 1280000);        // 640,000
  signed char* w8f  = (signed char*)(ws + 1920000);  // 212,992
  signed char* w8b  = (signed char*)(ws + 2132992);  // 212,992
  float* sclf  = (float*)(ws + 2345984);      // 3,200
  float* sclb  = (float*)(ws + 2349184);      // 3,200
  float* bgf   = (float*)(ws + 2352384);      // 3,200
  float* bgb   = (float*)(ws + 2355584);      // 3,200 -> end 2,358,784
  float* pooled= (float*)(ws + 2359296);      // 13,107,200
  float* x2p   = (float*)(ws + 15466496);     // 13,107,200
  u16*  xWf    = (u16*)(ws + 28573696);       // 13,107,200
  u16*  xWb    = (u16*)(ws + 41680896);       // 13,107,200
  float* h_ws  = (float*)(ws + 54788096);     // 13,107,200 -> end 67,895,296
  float* a_ws  = (float*)(ws + 67895296);     // 32,768
  float* amax_ws=(float*)(ws + 67928064);     // 128 (end ~67.93MB)
  float* x1_att= (float*)(ws + 28573696);     // overlay: xWf dead after k41

  k0_cvt  <<<dim3(1250), dim3(256), 0, stream>>>(wq, wk, wihf, wihb,
                                                 bihf, bhhf, bihb, bhhb,
                                                 wqb, wkb, wihfb, wihbb, bgf, bgb);
  k0b_quant<<<dim3(416), dim3(256), 0, stream>>>(whhf, whhb, w8f, w8b, sclf, sclb);
  k3_xw   <<<dim3(256),  dim3(512), 0, stream>>>(x1, seq, wihfb, wihbb, bgf, bgb, xWf, xWb);
  k41_fused<<<dim3(4112), dim3(512), 0, stream>>>(xWf, xWb, w8f, w8b, sclf, sclb, seq, h_ws,
                                                  x2, wqb, bq, wkb, bk, pooled);
  k2_x2p  <<<dim3(1024), dim3(256), 0, stream>>>(pooled, wmha, bmha, x2p);
  k4b_fill<<<dim3(32),   dim3(256), 0, stream>>>(seq, h_ws, wattn, a_ws, amax_ws);
  k5_attn <<<dim3(256),  dim3(256), 0, stream>>>(h_ws, a_ws, amax_ws, x1_att);
  k6_out  <<<dim3(1024), dim3(256), 0, stream>>>(x1_att, x2p, wmlp, bmlp, seq, out);
}

// Round 17
// 1103.134 us; speedup vs baseline: 1.1172x; 1.1172x over previous
//
// NeRTModel_60997125538302 — round 17: REVERT to round 15 (best measured, 1102us).
// r16's 404-layout MFMA scores caused 3x bank conflicts (808B lane stride = dword-stride
// 202 = 10 mod 32) + fragmented short4v loads -> 813us fused (regression). The r9-style
// dot-product score phase with broadcast k-reads is the best measured form.
// Config: k0 cvt, k0b i8-quant W_hh, k3 xW MFMA, k41 fused (LSTM blocks 0-15 @37KB LDS,
// 6 reg + 4 pool i8 pairs, setprio(2); pooling blocks 16+ @79.6KB), k2 x2p, k4b fill+a[],
// k5 grid-256 exact cumsum, k6 out MLP.

#include <hip/hip_runtime.h>
#include <hip/hip_bf16.h>
#include <cstdint>
#include <cstddef>

typedef unsigned short u16;
typedef __attribute__((ext_vector_type(8))) short short8v;
typedef __attribute__((ext_vector_type(4))) short short4v;
typedef __attribute__((ext_vector_type(4))) float f32x4;
typedef __attribute__((ext_vector_type(4))) int i32x4;

#define MFMA16 __builtin_amdgcn_mfma_f32_16x16x32_bf16
#define MFMAI8 __builtin_amdgcn_mfma_i32_16x16x64_i8

__device__ __forceinline__ float bf2f(u16 u){
  union { unsigned int i; float f; } v; v.i = ((unsigned int)u) << 16; return v.f;
}
__device__ __forceinline__ u16 f2bf(float f){
  union { float f; unsigned int u; } v; v.f = f;
  unsigned int r = v.u + 0x7FFFu + ((v.u >> 16) & 1u);
  return (u16)(r >> 16);
}
__device__ __forceinline__ short8v szero(){
  short8v z;
  #pragma unroll
  for (int i = 0; i < 8; i++) z[i] = 0;
  return z;
}
__device__ __forceinline__ float sigm(float x){ return 1.0f/(1.0f + __expf(-x)); }
__device__ __forceinline__ float tanh_u(float x){
  float e = __expf(2.f*x);              // overflow -> inf -> tanh -> 1 (no NaN)
  return 1.f - 2.f/(e + 1.f);
}
// LDS-visibility-only barrier: does NOT drain vmcnt.
__device__ __forceinline__ void lds_barrier(){
  asm volatile("s_waitcnt lgkmcnt(0)" ::: "memory");
  __builtin_amdgcn_s_barrier();
  __builtin_amdgcn_sched_barrier(0);
}

// ---------------- K0: convert non-recurrent weights f32 -> bf16; fuse LSTM biases ----------------
__global__ void k0_cvt(const float* __restrict__ wq, const float* __restrict__ wk,
                       const float* __restrict__ wihf, const float* __restrict__ wihb,
                       const float* __restrict__ bihf, const float* __restrict__ bhhf,
                       const float* __restrict__ bihb, const float* __restrict__ bhhb,
                       u16* __restrict__ wqb, u16* __restrict__ wkb,
                       u16* __restrict__ wihfb, u16* __restrict__ wihbb,
                       float* __restrict__ bgf, float* __restrict__ bgb){
  int i = blockIdx.x*256 + threadIdx.x;
  if (i < 160000){ wqb[i] = f2bf(wq[i]); wkb[i] = f2bf(wk[i]); }
  if (i < 320000){ wihfb[i] = f2bf(wihf[i]); wihbb[i] = f2bf(wihb[i]); }
  if (i < 800){ bgf[i] = bihf[i] + bhhf[i]; bgb[i] = bihb[i] + bhhb[i]; }
}

// ---------------- K0b: row-quantize W_hh -> i8 [4 gate][208 row][256 k] + scales ----------------
__global__ void k0b_quant(const float* __restrict__ whhf, const float* __restrict__ whhb,
                          signed char* __restrict__ w8f, signed char* __restrict__ w8b,
                          float* __restrict__ sclf, float* __restrict__ sclb){
  const int tid = threadIdx.x, lane = tid & 63, wv = tid >> 6;
  const int widx = blockIdx.x*4 + wv;              // 0..1663
  if (widx < 1600){
    int dir = widx / 800, g = widx - dir*800;
    const float* src = (dir ? whhb : whhf) + (size_t)g*200;
    float mx = 0.f;
    for (int j = lane; j < 200; j += 64) mx = fmaxf(mx, fabsf(src[j]));
    #pragma unroll
    for (int m = 32; m > 0; m >>= 1) mx = fmaxf(mx, __shfl_xor(mx, m, 64));
    float inv = (mx > 0.f) ? 127.f/mx : 0.f;
    int gt = g / 200, hl = g - gt*200;
    signed char* dst = (dir ? w8b : w8f) + (size_t)(gt*208 + hl)*256;
    int e0 = lane*4;
    unsigned int pack = 0u;
    if (e0 < 200){
      #pragma unroll
      for (int r = 0; r < 4; r++){
        int qv = __float2int_rn(src[e0+r]*inv);
        pack |= ((unsigned int)(qv & 255)) << (8*r);
      }
    }
    ((unsigned int*)dst)[lane] = pack;               // lanes 50..63 zero the k-pad
    if (lane == 0) (dir ? sclb : sclf)[g] = mx / 16129.f;   // mx / 127^2
  } else {
    int pr = widx - 1600;                            // 64 pad rows
    int dir = pr >> 5, rem = pr & 31, gt = rem >> 3, hl = 200 + (rem & 7);
    signed char* dst = (dir ? w8b : w8f) + (size_t)(gt*208 + hl)*256;
    ((unsigned int*)dst)[lane] = 0u;
  }
}

// ---------------- K3: xW = x @ W_ih^T + (b_ih+b_hh), layout [t][b32][hu][gt] bf16 ----------------
__launch_bounds__(512)
__global__ void k3_xw(const float* __restrict__ x1, const int* __restrict__ seq,
                      const u16* __restrict__ wihfb, const u16* __restrict__ wihbb,
                      const float* __restrict__ bgf, const float* __restrict__ bgb,
                      u16* __restrict__ xWf, u16* __restrict__ xWb){
  __shared__ u16 xf[12800];
  __shared__ u16 xb[12800];
  const int tid = threadIdx.x;
  const int t = blockIdx.x;
  for (int i = tid; i < 3200; i += 512){
    int b = i / 100, e4 = i - b*100;
    f32x4 vf = *(const f32x4*)&x1[((size_t)b*256 + t)*400 + e4*4];
    int rb = seq[b] - 1 - t; if (rb < 0) rb = 0;     // clip(L-1-t, 0, T-1)
    f32x4 vb = *(const f32x4*)&x1[((size_t)b*256 + rb)*400 + e4*4];
    short4v sf, sb;
    #pragma unroll
    for (int r = 0; r < 4; r++){ sf[r] = f2bf(vf[r]); sb[r] = f2bf(vb[r]); }
    ((short4v*)xf)[i] = sf;
    ((short4v*)xb)[i] = sb;
  }
  __syncthreads();
  const int lane = tid & 63, wv = tid >> 6;
  const int dir = wv >> 2, wl = wv & 3;
  const u16* xs = dir ? xb : xf;
  const u16* W  = dir ? wihbb : wihfb;
  const float* bg = dir ? bgb : bgf;
  u16* xW = dir ? xWb : xWf;
  const int q = lane & 15, kg = lane >> 4;
  short8v A[2][13];
  #pragma unroll
  for (int mt = 0; mt < 2; mt++)
    #pragma unroll
    for (int ksi = 0; ksi < 13; ksi++){
      int e0 = ksi*32 + kg*8;
      A[mt][ksi] = (e0 < 400) ? *(const short8v*)&xs[(mt*16 + q)*400 + e0] : szero();
    }
  for (int nt = wl; nt < 50; nt += 4){
    int g = nt*16 + q;                       // gate row 0..799
    float bv = bg[g];
    f32x4 acc0, acc1;
    acc0[0]=bv; acc0[1]=bv; acc0[2]=bv; acc0[3]=bv; acc1 = acc0;
    const u16* wrow = W + (size_t)g*400;
    #pragma unroll
    for (int ksi = 0; ksi < 13; ksi++){
      int e0 = ksi*32 + kg*8;
      short8v bf = (e0 < 400) ? *(const short8v*)&wrow[e0] : szero();
      acc0 = MFMA16(A[0][ksi], bf, acc0, 0,0,0);
      acc1 = MFMA16(A[1][ksi], bf, acc1, 0,0,0);
    }
    int gt = g / 200, hu = g - gt*200;
    #pragma unroll
    for (int r = 0; r < 4; r++){
      int bl = kg*4 + r;                     // D rows = batch rows
      xW[(((size_t)t*32 +      bl)*200 + hu)*4 + gt] = f2bf(acc0[r]);
      xW[(((size_t)t*32 + 16 + bl)*200 + hu)*4 + gt] = f2bf(acc1[r]);
    }
  }
}

// ---------------- K41: FUSED LSTM (blocks 0-15, 37KB LDS) + pooling (blocks 16+). ----------------
__device__ __forceinline__ void store_gate_f32(int p, const i32x4& acc, int q, int kg,
                                               float* gates, const float* scl_s){
  int gt = p/13, nt = p - gt*13;
  int hu0 = nt*16 + kg*4;
  if (hu0 < 200 && q < 4){
    const f32x4 s4 = *(const f32x4*)&scl_s[gt*200 + hu0];
    #pragma unroll
    for (int r = 0; r < 4; r++)
      gates[q*804 + (hu0+r)*4 + gt] = (float)acc[r]*s4[r];
  }
}

__launch_bounds__(512)
__global__ void k41_fused(const u16* __restrict__ xWf, const u16* __restrict__ xWb,
                          const signed char* __restrict__ w8f, const signed char* __restrict__ w8b,
                          const float* __restrict__ sclf, const float* __restrict__ sclb,
                          const int* __restrict__ seq, float* __restrict__ h_ws,
                          const float* __restrict__ x2,
                          const u16* __restrict__ wqb, const float* __restrict__ bq,
                          const u16* __restrict__ wkb, const float* __restrict__ bk,
                          float* __restrict__ pooled){
  __shared__ __align__(16) char smem[79616];
  const int tid = threadIdx.x;
  const int bid = blockIdx.x;
  const int lane = tid & 63, wv = tid >> 6;
  const int q = lane & 15, kg = lane >> 4;

  if (bid < 16){
    // ============ LSTM path: 6 reg pairs + 4 LDS pool pairs; LDS 37KB ============
    __builtin_amdgcn_s_setprio(2);                     // protect recurrence critical path
    signed char* h8   = (signed char*)smem;            // 4,608
    float* gates      = (float*)(smem + 4608);         // 12,864 -> 17,472
    i32x4* pool       = (i32x4*)(smem + 17472);        // 16,384 -> 33,856
    float* scl_s      = (float*)(smem + 33856);        // 3,200 -> 37,056
    int* Ls           = (int*)(smem + 37056);          // 16 -> 37,072
    const int dir = bid >> 3, grp = bid & 7;
    const u16* xWd = dir ? xWb : xWf;
    const signed char* w8 = dir ? w8b : w8f;
    const float* scl = dir ? sclb : sclf;
    if (tid < 4) Ls[tid] = seq[grp*4 + tid];
    for (int i = tid; i < 1152; i += 512) ((int*)h8)[i] = 0;
    for (int i = tid; i < 800; i += 512) scl_s[i] = scl[i];
    for (int idx = tid; idx < 1024; idx += 512){
      int s = idx >> 8, rem = idx & 255;
      int ksi = rem >> 6, l = rem & 63;
      int qq = l & 15, kk = l >> 4;
      pool[idx] = *(const i32x4*)&w8[(size_t)(3*208 + (9+s)*16 + qq)*256 + ksi*64 + kk*16];
    }
    i32x4 Wr[6][4];
    #pragma unroll
    for (int j = 0; j < 6; j++){
      int p = wv + 8*j, gt = p/13, nt = p - gt*13;
      #pragma unroll
      for (int ksi = 0; ksi < 4; ksi++)
        Wr[j][ksi] = *(const i32x4*)&w8[(size_t)(gt*208 + nt*16 + q)*256 + ksi*64 + kg*16];
    }
    float cst0 = 0.f, cst1 = 0.f;
    const int c0 = tid,        b0c = c0/200, hu0c = c0 - b0c*200;
    const int qd1 = tid + 512;
    const int b1c = qd1/200,   hu1c = qd1 - b1c*200;
    const int xoff0 = ((grp*4 + b0c)*200 + hu0c)*4;
    const int xoff1 = ((grp*4 + b1c)*200 + hu1c)*4;
    short4v xc0 = *(const short4v*)&xWd[xoff0];
    short4v xc1 = {0,0,0,0};
    if (tid < 288) xc1 = *(const short4v*)&xWd[xoff1];
    __syncthreads();
    #pragma unroll 1
    for (int t = 0; t < 256; t++){
      int tn = (t + 1 < 256) ? t + 1 : 255;
      const u16* xwn = xWd + (size_t)tn*25600;
      short4v xn0 = *(const short4v*)&xwn[xoff0];
      short4v xn1 = {0,0,0,0};
      if (tid < 288) xn1 = *(const short4v*)&xwn[xoff1];
      i32x4 bh[4];
      #pragma unroll
      for (int ksi = 0; ksi < 4; ksi++)
        bh[ksi] = *(const i32x4*)&h8[q*288 + ksi*64 + kg*16];
      #pragma unroll
      for (int j = 0; j < 6; j++){
        i32x4 acc = {0,0,0,0};
        #pragma unroll
        for (int ksi = 0; ksi < 4; ksi++)
          acc = MFMAI8(Wr[j][ksi], bh[ksi], acc, 0,0,0);
        store_gate_f32(wv + 8*j, acc, q, kg, gates, scl_s);
      }
      if (wv < 4){                                   // pool pair p = 48+wv
        i32x4 acc = {0,0,0,0};
        #pragma unroll
        for (int ksi = 0; ksi < 4; ksi++)
          acc = MFMAI8(pool[(wv*4 + ksi)*64 + lane], bh[ksi], acc, 0,0,0);
        store_gate_f32(48 + wv, acc, q, kg, gates, scl_s);
      }
      lds_barrier();
      {
        const f32x4 g4 = *(const f32x4*)&gates[b0c*804 + hu0c*4];
        float gi = g4[0] + bf2f((u16)xc0[0]);
        float gf = g4[1] + bf2f((u16)xc0[1]);
        float gg = g4[2] + bf2f((u16)xc0[2]);
        float go = g4[3] + bf2f((u16)xc0[3]);
        float c = sigm(gf)*cst0 + sigm(gi)*tanh_u(gg);
        cst0 = c;
        float hv = sigm(go)*tanh_u(c);
        h8[b0c*288 + hu0c] = (signed char)__float2int_rn(hv*127.f);
        int gb = grp*4 + b0c;
        if (dir == 0){
          h_ws[((size_t)gb*256 + t)*400 + hu0c] = hv;
        } else {
          int tp = Ls[b0c] - 1 - t;
          if (tp >= 0) h_ws[((size_t)gb*256 + tp)*400 + 200 + hu0c] = hv;
        }
      }
      if (tid < 288){
        const f32x4 g4 = *(const f32x4*)&gates[b1c*804 + hu1c*4];
        float gi = g4[0] + bf2f((u16)xc1[0]);
        float gf = g4[1] + bf2f((u16)xc1[1]);
        float gg = g4[2] + bf2f((u16)xc1[2]);
        float go = g4[3] + bf2f((u16)xc1[3]);
        float c = sigm(gf)*cst1 + sigm(gi)*tanh_u(gg);
        cst1 = c;
        float hv = sigm(go)*tanh_u(c);
        h8[b1c*288 + hu1c] = (signed char)__float2int_rn(hv*127.f);
        int gb = grp*4 + b1c;
        if (dir == 0){
          h_ws[((size_t)gb*256 + t)*400 + hu1c] = hv;
        } else {
          int tp = Ls[b1c] - 1 - t;
          if (tp >= 0) h_ws[((size_t)gb*256 + tp)*400 + 200 + hu1c] = hv;
        }
      }
      lds_barrier();
      xc0 = xn0; xc1 = xn1;
    }
  } else {
    // ============ pooling path (r9 k1 math; 8-way wave split) ============
    u16* tok0  = (u16*)smem;                 // 25,600
    u16* qsb   = (u16*)(smem + 25600);       // 25,856 -> 51,456
    u16* ksb   = (u16*)(smem + 51456);       // 25,856 -> 77,312
    float* msum= (float*)(smem + 77312);     // 2,048 -> 79,360
    float* tval= (float*)(smem + 79360);     // 128
    float* attw= (float*)(smem + 79488);     // 128 -> 79,616
    const int kb = bid - 16;
    const size_t n0 = (size_t)kb * 2;
    const float* src = x2 + n0*6400;
    msum[tid & 511] = 0.f;
    for (int i = tid; i < 3200; i += 512){
      f32x4 v = *(const f32x4*)&src[(size_t)i*4];
      short4v s; s[0]=f2bf(v[0]); s[1]=f2bf(v[1]); s[2]=f2bf(v[2]); s[3]=f2bf(v[3]);
      int j = i / 1600, r = i - j*1600;
      ((short4v*)(tok0 + j*6400))[r] = s;
    }
    __syncthreads();
    {
      const int proj = wv >> 2;              // waves 0-3: q, 4-7: k
      const int jn   = (wv >> 1) & 1;
      const int half = wv & 1;
      const int ntbase = half ? 13 : 0;
      const int ntcnt  = half ? 12 : 13;
      const u16* W    = proj ? wkb : wqb;
      const float* bias = proj ? bk : bq;
      const u16* tokj = tok0 + jn*6400;
      u16* dst = (proj ? ksb : qsb) + jn*6464;
      short8v A[13];
      #pragma unroll
      for (int ksi = 0; ksi < 13; ksi++){
        int e0 = ksi*32 + kg*8;
        A[ksi] = (e0 < 400) ? *(const short8v*)&tokj[q*400 + e0] : szero();
      }
      for (int ti = 0; ti < ntcnt; ti++){
        int col = (ntbase + ti)*16 + q;
        float bv = bias[col];
        f32x4 acc;
        acc[0]=bv; acc[1]=bv; acc[2]=bv; acc[3]=bv;
        const u16* wrow = W + (size_t)col*400;
        #pragma unroll
        for (int ksi = 0; ksi < 13; ksi++){
          int e0 = ksi*32 + kg*8;
          short8v bf = (e0 < 400) ? *(const short8v*)&wrow[e0] : szero();
          acc = MFMA16(A[ksi], bf, acc, 0, 0, 0);
        }
        #pragma unroll
        for (int r = 0; r < 4; r++)          // D: row=(l>>4)*4+r, col=l&15
          dst[(kg*4+r)*404 + col] = f2bf(acc[r]);
      }
    }
    __syncthreads();
    for (int rr = 0; rr < 2; rr++){
      int row = tid + rr*512;
      if (row < 640){
        int j = row / 320, r2 = row - j*320;
        int hh = r2 >> 4, sq = r2 & 15;
        const u16* qrow = qsb + j*6464 + sq*404 + hh*20;
        float qv[20];
        #pragma unroll
        for (int d5 = 0; d5 < 5; d5++){
          short4v v = *(const short4v*)&qrow[d5*4];
          qv[d5*4+0]=bf2f((u16)v[0]); qv[d5*4+1]=bf2f((u16)v[1]);
          qv[d5*4+2]=bf2f((u16)v[2]); qv[d5*4+3]=bf2f((u16)v[3]);
        }
        float sc[16]; float mx = -1e30f;
        const u16* kbase = ksb + j*6464 + hh*20;
        #pragma unroll
        for (int sk = 0; sk < 16; sk++){
          const u16* krow = kbase + sk*404;
          float s = 0.f;
          #pragma unroll
          for (int d5 = 0; d5 < 5; d5++){
            short4v v = *(const short4v*)&krow[d5*4];
            s += qv[d5*4+0]*bf2f((u16)v[0]) + qv[d5*4+1]*bf2f((u16)v[1])
               + qv[d5*4+2]*bf2f((u16)v[2]) + qv[d5*4+3]*bf2f((u16)v[3]);
          }
          s *= 0.22360679775f;               // 1/sqrt(20)
          sc[sk] = s; mx = fmaxf(mx, s);
        }
        float sum = 0.f;
        #pragma unroll
        for (int sk = 0; sk < 16; sk++){ sc[sk] = __expf(sc[sk]-mx); sum += sc[sk]; }
        float inv = 0.05f/sum;               // fold the 1/20 head-mean in
        #pragma unroll
        for (int sk = 0; sk < 16; sk++){
          float v = sc[sk]*inv;
          v += __shfl_xor(v, 16, 64);
          v += __shfl_xor(v, 32, 64);
          if (kg == 0) atomicAdd(&msum[j*256 + sq*16 + sk], v);
        }
      }
    }
    __syncthreads();
    if (tid < 32){
      int j = tid >> 4, sq = tid & 15;
      float s = 0.f;
      #pragma unroll
      for (int sk = 0; sk < 16; sk++) s += msum[j*256 + sq*16+sk];
      tval[j*16 + sq] = s * 0.0625f;
    }
    __syncthreads();
    if (tid < 2){
      float mx = -1e30f;
      for (int i = 0; i < 16; i++) mx = fmaxf(mx, tval[tid*16+i]);
      float sum = 0.f; float ev[16];
      for (int i = 0; i < 16; i++){ ev[i] = __expf(tval[tid*16+i]-mx); sum += ev[i]; }
      float inv = 1.f/sum;
      for (int i = 0; i < 16; i++) attw[tid*16+i] = ev[i]*inv;
    }
    __syncthreads();
    for (int e = tid; e < 800; e += 512){
      int j = e / 400, c = e - j*400;
      float acc = 0.f;
      #pragma unroll
      for (int s = 0; s < 16; s++) acc += attw[j*16+s]*bf2f(tok0[j*6400 + s*400 + c]);
      pooled[(n0+j)*400 + c] = acc;
    }
  }
}

// ---------------- K2: x2p = pooled @ w_mlp_mha^T + b (f32 VALU) ----------------
__global__ void k2_x2p(const float* __restrict__ pooled, const float* __restrict__ wmha,
                       const float* __restrict__ bmha, float* __restrict__ x2p){
  __shared__ float rows[3200];
  const int tid = threadIdx.x;
  const size_t n0 = (size_t)blockIdx.x*8;
  for (int i = tid; i < 3200; i += 256) rows[i] = pooled[n0*400 + i];
  __syncthreads();
  for (int j = tid; j < 400; j += 256){
    float bv = bmha[j];
    float acc[8];
    #pragma unroll
    for (int r = 0; r < 8; r++) acc[r] = bv;
    const float* wr = wmha + (size_t)j*400;
    for (int e = 0; e < 400; e += 4){
      const f32x4 w4 = *(const f32x4*)&wr[e];
      #pragma unroll
      for (int r = 0; r < 8; r++){
        const f32x4 x4 = *(const f32x4*)&rows[r*400 + e];
        acc[r] += x4[0]*w4[0] + x4[1]*w4[1] + x4[2]*w4[2] + x4[3]*w4[3];
      }
    }
    #pragma unroll
    for (int r = 0; r < 8; r++) x2p[(n0+r)*400 + j] = acc[r];
  }
}

// ---------------- K4b: fill bwd rows t>=L AND compute a[b][t] + per-b max ----------------
__global__ void k4b_fill(const int* __restrict__ seq, float* __restrict__ h_ws,
                         const float* __restrict__ wattn,
                         float* __restrict__ a_ws, float* __restrict__ amax_ws){
  __shared__ float a_lds[256];
  const int b = blockIdx.x;
  const int tid = threadIdx.x;
  const int lane = tid & 63, wv = tid >> 6;
  const int L = seq[b];
  const int cnt = (256 - L)*200;
  const float* srcf = h_ws + ((size_t)b*256 + (L-1))*400 + 200;
  for (int i = tid; i < cnt; i += 256){
    int tt = L + i/200, cc = i - (i/200)*200;
    h_ws[((size_t)b*256 + tt)*400 + 200 + cc] = srcf[cc];
  }
  __syncthreads();
  for (int row = wv*64; row < wv*64 + 64; row++){
    float s = 0.f;
    for (int j = lane; j < 400; j += 64)
      s += h_ws[((size_t)b*256 + row)*400 + j] * wattn[j];
    #pragma unroll
    for (int m = 32; m > 0; m >>= 1) s += __shfl_xor(s, m, 64);
    if (lane == 0) a_lds[row] = s;
  }
  __syncthreads();
  a_ws[b*256 + tid] = a_lds[tid];
  if (tid < 64){
    float m = fmaxf(fmaxf(a_lds[tid], a_lds[tid+64]), fmaxf(a_lds[tid+128], a_lds[tid+192]));
    #pragma unroll
    for (int mm = 32; mm > 0; mm >>= 1) m = fmaxf(m, __shfl_xor(m, mm, 64));
    if (tid == 0) amax_ws[b] = m;
  }
}

// ---------------- K5: causal attention as exact cumsum (const per-b max). grid 256. ----------------
__launch_bounds__(256)
__global__ void k5_attn(const float* __restrict__ h_ws, const float* __restrict__ a_ws,
                        const float* __restrict__ amax_ws, float* __restrict__ x1_att){
  __shared__ float tile[256*52];       // [t][col-chunk 50, pad 52], in-place h -> out
  __shared__ float wl[256];
  const int tid = threadIdx.x;
  const int b = blockIdx.x >> 3, ch = blockIdx.x & 7;
  const int c0 = ch*50;
  wl[tid] = __expf(a_ws[b*256 + tid] - amax_ws[b]);
  for (int i = tid; i < 12800; i += 256){
    int r = i / 50, c = i - r*50;
    tile[r*52 + c] = h_ws[((size_t)b*256 + r)*400 + c0 + c];
  }
  __syncthreads();
  if (tid < 50){
    float den = 0.f, num = 0.f;
    #pragma unroll 4
    for (int t = 0; t < 256; t++){
      float w = wl[t];
      den += w;
      num += w * tile[t*52 + tid];
      tile[t*52 + tid] = num/den;
    }
  }
  __syncthreads();
  for (int i = tid; i < 12800; i += 256){
    int r = i / 50, c = i - r*50;
    x1_att[((size_t)b*256 + r)*400 + c0 + c] = tile[r*52 + c];
  }
}

// ---------------- K6: out = [x1_att ; x2p] @ w_mlp^T + b, masked, f32 ----------------
__global__ void k6_out(const float* __restrict__ x1_att, const float* __restrict__ x2p,
                       const float* __restrict__ wmlp, const float* __restrict__ bmlp,
                       const int* __restrict__ seq, float* __restrict__ out){
  __shared__ float rows[8*800];
  const int tid = threadIdx.x;
  const size_t n0 = (size_t)blockIdx.x*8;
  const int b = (int)(n0 >> 8), t0 = (int)(n0 & 255);
  const int L = seq[b];
  for (int i = tid; i < 3200; i += 256){
    int r = i / 400, e = i - r*400;
    rows[r*800 + e]       = x1_att[(n0 + r)*400 + e];
    rows[r*800 + 400 + e] = x2p  [(n0 + r)*400 + e];
  }
  __syncthreads();
  for (int e = tid; e < 400; e += 256){
    float bv = bmlp[e];
    float acc[8];
    #pragma unroll
    for (int r = 0; r < 8; r++) acc[r] = bv;
    const float* wr = wmlp + (size_t)e*800;
    for (int j = 0; j < 800; j += 4){
      const f32x4 w4 = *(const f32x4*)&wr[j];
      #pragma unroll
      for (int r = 0; r < 8; r++){
        const f32x4 x4 = *(const f32x4*)&rows[r*800 + j];
        acc[r] += x4[0]*w4[0] + x4[1]*w4[1] + x4[2]*w4[2] + x4[3]*w4[3];
      }
    }
    #pragma unroll
    for (int r = 0; r < 8; r++){
      float v = (t0 + r < L) ? acc[r] : 0.f;
      out[(n0 + r)*400 + e] = v;
    }
  }
}

extern "C" void kernel_launch(void* const* d_in, const int* in_sizes, int n_in,
                              void* d_out, int out_size, void* d_ws, size_t ws_size,
                              hipStream_t stream){
  const float* x1   = (const float*)d_in[0];
  const float* x2   = (const float*)d_in[1];
  // d_in[2] = cate: unused by the reference
  const int*   seq  = (const int*)d_in[3];
  const float* wihf = (const float*)d_in[4];
  const float* whhf = (const float*)d_in[5];
  const float* bihf = (const float*)d_in[6];
  const float* bhhf = (const float*)d_in[7];
  const float* wihb = (const float*)d_in[8];
  const float* whhb = (const float*)d_in[9];
  const float* bihb = (const float*)d_in[10];
  const float* bhhb = (const float*)d_in[11];
  const float* wq   = (const float*)d_in[12];
  const float* bq   = (const float*)d_in[13];
  const float* wk   = (const float*)d_in[14];
  const float* bk   = (const float*)d_in[15];
  const float* wmha = (const float*)d_in[16];
  const float* bmha = (const float*)d_in[17];
  const float* wattn= (const float*)d_in[18];
  // d_in[19] = b_attn: cancels in softmax
  const float* wmlp = (const float*)d_in[20];
  const float* bmlp = (const float*)d_in[21];
  float* out = (float*)d_out;

  char* ws = (char*)d_ws;
  u16*  wqb    = (u16*)(ws + 0);              // 320,000 B
  u16*  wkb    = (u16*)(ws + 320000);         // 320,000
  u16*  wihfb  = (u16*)(ws + 640000);         // 640,000
  u16*  wihbb  = (u16*)(ws + 1280000);        // 640,000
  signed char* w8f  = (signed char*)(ws + 1920000);  // 212,992
  signed char* w8b  = (signed char*)(ws + 2132992);  // 212,992
  float* sclf  = (float*)(ws + 2345984);      // 3,200
  float* sclb  = (float*)(ws + 2349184);      // 3,200
  float* bgf   = (float*)(ws + 2352384);      // 3,200
  float* bgb   = (float*)(ws + 2355584);      // 3,200 -> end 2,358,784
  float* pooled= (float*)(ws + 2359296);      // 13,107,200
  float* x2p   = (float*)(ws + 15466496);     // 13,107,200
  u16*  xWf    = (u16*)(ws + 28573696);       // 13,107,200
  u16*  xWb    = (u16*)(ws + 41680896);       // 13,107,200
  float* h_ws  = (float*)(ws + 54788096);     // 13,107,200 -> end 67,895,296
  float* a_ws  = (float*)(ws + 67895296);     // 32,768
  float* amax_ws=(float*)(ws + 67928064);     // 128 (end ~67.93MB)
  float* x1_att= (float*)(ws + 28573696);     // overlay: xWf dead after k41

  k0_cvt  <<<dim3(1250), dim3(256), 0, stream>>>(wq, wk, wihf, wihb,
                                                 bihf, bhhf, bihb, bhhb,
                                                 wqb, wkb, wihfb, wihbb, bgf, bgb);
  k0b_quant<<<dim3(416), dim3(256), 0, stream>>>(whhf, whhb, w8f, w8b, sclf, sclb);
  k3_xw   <<<dim3(256),  dim3(512), 0, stream>>>(x1, seq, wihfb, wihbb, bgf, bgb, xWf, xWb);
  k41_fused<<<dim3(4112), dim3(512), 0, stream>>>(xWf, xWb, w8f, w8b, sclf, sclb, seq, h_ws,
                                                  x2, wqb, bq, wkb, bk, pooled);
  k2_x2p  <<<dim3(1024), dim3(256), 0, stream>>>(pooled, wmha, bmha, x2p);
  k4b_fill<<<dim3(32),   dim3(256), 0, stream>>>(seq, h_ws, wattn, a_ws, amax_ws);
  k5_attn <<<dim3(256),  dim3(256), 0, stream>>>(h_ws, a_ws, amax_ws, x1_att);
  k6_out  <<<dim3(1024), dim3(256), 0, stream>>>(x1_att, x2p, wmlp, bmlp, seq, out);
}

// Round 18
// 956.236 us; speedup vs baseline: 1.2888x; 1.1536x over previous
//
// NeRTModel_60997125538302 — round 18: fused pooling as TWO independent 256-thr halves.
// r17 confirmed plateau 1103 (fused 680). Anomaly: fused pooling @8 waves/CU is 35%
// slower than r13's identical math @8 waves/CU (2x256-thr blocks, <=473us on 256 CUs
// -> 505 normalized). Cause: 512-wide block shape (score pass-2 leaves 3/4 idle; all
// phases convoyed by 512-wide barriers). Fix: pooling block = two independent r13-style
// 256-thread sub-blocks (half = tid>>8, own 79.6KB LDS slice; 155.5KB static total,
// r7 proved >144KB static works). Both halves run the same barrier count -> legal.
// Grid 16 + 2048 (4 news/block). LSTM path and all other kernels = r17.

#include <hip/hip_runtime.h>
#include <hip/hip_bf16.h>
#include <cstdint>
#include <cstddef>

typedef unsigned short u16;
typedef __attribute__((ext_vector_type(8))) short short8v;
typedef __attribute__((ext_vector_type(4))) short short4v;
typedef __attribute__((ext_vector_type(4))) float f32x4;
typedef __attribute__((ext_vector_type(4))) int i32x4;

#define MFMA16 __builtin_amdgcn_mfma_f32_16x16x32_bf16
#define MFMAI8 __builtin_amdgcn_mfma_i32_16x16x64_i8

__device__ __forceinline__ float bf2f(u16 u){
  union { unsigned int i; float f; } v; v.i = ((unsigned int)u) << 16; return v.f;
}
__device__ __forceinline__ u16 f2bf(float f){
  union { float f; unsigned int u; } v; v.f = f;
  unsigned int r = v.u + 0x7FFFu + ((v.u >> 16) & 1u);
  return (u16)(r >> 16);
}
__device__ __forceinline__ short8v szero(){
  short8v z;
  #pragma unroll
  for (int i = 0; i < 8; i++) z[i] = 0;
  return z;
}
__device__ __forceinline__ float sigm(float x){ return 1.0f/(1.0f + __expf(-x)); }
__device__ __forceinline__ float tanh_u(float x){
  float e = __expf(2.f*x);              // overflow -> inf -> tanh -> 1 (no NaN)
  return 1.f - 2.f/(e + 1.f);
}
// LDS-visibility-only barrier: does NOT drain vmcnt.
__device__ __forceinline__ void lds_barrier(){
  asm volatile("s_waitcnt lgkmcnt(0)" ::: "memory");
  __builtin_amdgcn_s_barrier();
  __builtin_amdgcn_sched_barrier(0);
}

// ---------------- K0: convert non-recurrent weights f32 -> bf16; fuse LSTM biases ----------------
__global__ void k0_cvt(const float* __restrict__ wq, const float* __restrict__ wk,
                       const float* __restrict__ wihf, const float* __restrict__ wihb,
                       const float* __restrict__ bihf, const float* __restrict__ bhhf,
                       const float* __restrict__ bihb, const float* __restrict__ bhhb,
                       u16* __restrict__ wqb, u16* __restrict__ wkb,
                       u16* __restrict__ wihfb, u16* __restrict__ wihbb,
                       float* __restrict__ bgf, float* __restrict__ bgb){
  int i = blockIdx.x*256 + threadIdx.x;
  if (i < 160000){ wqb[i] = f2bf(wq[i]); wkb[i] = f2bf(wk[i]); }
  if (i < 320000){ wihfb[i] = f2bf(wihf[i]); wihbb[i] = f2bf(wihb[i]); }
  if (i < 800){ bgf[i] = bihf[i] + bhhf[i]; bgb[i] = bihb[i] + bhhb[i]; }
}

// ---------------- K0b: row-quantize W_hh -> i8 [4 gate][208 row][256 k] + scales ----------------
__global__ void k0b_quant(const float* __restrict__ whhf, const float* __restrict__ whhb,
                          signed char* __restrict__ w8f, signed char* __restrict__ w8b,
                          float* __restrict__ sclf, float* __restrict__ sclb){
  const int tid = threadIdx.x, lane = tid & 63, wv = tid >> 6;
  const int widx = blockIdx.x*4 + wv;              // 0..1663
  if (widx < 1600){
    int dir = widx / 800, g = widx - dir*800;
    const float* src = (dir ? whhb : whhf) + (size_t)g*200;
    float mx = 0.f;
    for (int j = lane; j < 200; j += 64) mx = fmaxf(mx, fabsf(src[j]));
    #pragma unroll
    for (int m = 32; m > 0; m >>= 1) mx = fmaxf(mx, __shfl_xor(mx, m, 64));
    float inv = (mx > 0.f) ? 127.f/mx : 0.f;
    int gt = g / 200, hl = g - gt*200;
    signed char* dst = (dir ? w8b : w8f) + (size_t)(gt*208 + hl)*256;
    int e0 = lane*4;
    unsigned int pack = 0u;
    if (e0 < 200){
      #pragma unroll
      for (int r = 0; r < 4; r++){
        int qv = __float2int_rn(src[e0+r]*inv);
        pack |= ((unsigned int)(qv & 255)) << (8*r);
      }
    }
    ((unsigned int*)dst)[lane] = pack;               // lanes 50..63 zero the k-pad
    if (lane == 0) (dir ? sclb : sclf)[g] = mx / 16129.f;   // mx / 127^2
  } else {
    int pr = widx - 1600;                            // 64 pad rows
    int dir = pr >> 5, rem = pr & 31, gt = rem >> 3, hl = 200 + (rem & 7);
    signed char* dst = (dir ? w8b : w8f) + (size_t)(gt*208 + hl)*256;
    ((unsigned int*)dst)[lane] = 0u;
  }
}

// ---------------- K3: xW = x @ W_ih^T + (b_ih+b_hh), layout [t][b32][hu][gt] bf16 ----------------
__launch_bounds__(512)
__global__ void k3_xw(const float* __restrict__ x1, const int* __restrict__ seq,
                      const u16* __restrict__ wihfb, const u16* __restrict__ wihbb,
                      const float* __restrict__ bgf, const float* __restrict__ bgb,
                      u16* __restrict__ xWf, u16* __restrict__ xWb){
  __shared__ u16 xf[12800];
  __shared__ u16 xb[12800];
  const int tid = threadIdx.x;
  const int t = blockIdx.x;
  for (int i = tid; i < 3200; i += 512){
    int b = i / 100, e4 = i - b*100;
    f32x4 vf = *(const f32x4*)&x1[((size_t)b*256 + t)*400 + e4*4];
    int rb = seq[b] - 1 - t; if (rb < 0) rb = 0;     // clip(L-1-t, 0, T-1)
    f32x4 vb = *(const f32x4*)&x1[((size_t)b*256 + rb)*400 + e4*4];
    short4v sf, sb;
    #pragma unroll
    for (int r = 0; r < 4; r++){ sf[r] = f2bf(vf[r]); sb[r] = f2bf(vb[r]); }
    ((short4v*)xf)[i] = sf;
    ((short4v*)xb)[i] = sb;
  }
  __syncthreads();
  const int lane = tid & 63, wv = tid >> 6;
  const int dir = wv >> 2, wl = wv & 3;
  const u16* xs = dir ? xb : xf;
  const u16* W  = dir ? wihbb : wihfb;
  const float* bg = dir ? bgb : bgf;
  u16* xW = dir ? xWb : xWf;
  const int q = lane & 15, kg = lane >> 4;
  short8v A[2][13];
  #pragma unroll
  for (int mt = 0; mt < 2; mt++)
    #pragma unroll
    for (int ksi = 0; ksi < 13; ksi++){
      int e0 = ksi*32 + kg*8;
      A[mt][ksi] = (e0 < 400) ? *(const short8v*)&xs[(mt*16 + q)*400 + e0] : szero();
    }
  for (int nt = wl; nt < 50; nt += 4){
    int g = nt*16 + q;                       // gate row 0..799
    float bv = bg[g];
    f32x4 acc0, acc1;
    acc0[0]=bv; acc0[1]=bv; acc0[2]=bv; acc0[3]=bv; acc1 = acc0;
    const u16* wrow = W + (size_t)g*400;
    #pragma unroll
    for (int ksi = 0; ksi < 13; ksi++){
      int e0 = ksi*32 + kg*8;
      short8v bf = (e0 < 400) ? *(const short8v*)&wrow[e0] : szero();
      acc0 = MFMA16(A[0][ksi], bf, acc0, 0,0,0);
      acc1 = MFMA16(A[1][ksi], bf, acc1, 0,0,0);
    }
    int gt = g / 200, hu = g - gt*200;
    #pragma unroll
    for (int r = 0; r < 4; r++){
      int bl = kg*4 + r;                     // D rows = batch rows
      xW[(((size_t)t*32 +      bl)*200 + hu)*4 + gt] = f2bf(acc0[r]);
      xW[(((size_t)t*32 + 16 + bl)*200 + hu)*4 + gt] = f2bf(acc1[r]);
    }
  }
}

// ---------------- K41: FUSED LSTM (blocks 0-15) + pooling (blocks 16+, 2x256-thr halves). ----------------
__device__ __forceinline__ void store_gate_f32(int p, const i32x4& acc, int q, int kg,
                                               float* gates, const float* scl_s){
  int gt = p/13, nt = p - gt*13;
  int hu0 = nt*16 + kg*4;
  if (hu0 < 200 && q < 4){
    const f32x4 s4 = *(const f32x4*)&scl_s[gt*200 + hu0];
    #pragma unroll
    for (int r = 0; r < 4; r++)
      gates[q*804 + (hu0+r)*4 + gt] = (float)acc[r]*s4[r];
  }
}

__launch_bounds__(512)
__global__ void k41_fused(const u16* __restrict__ xWf, const u16* __restrict__ xWb,
                          const signed char* __restrict__ w8f, const signed char* __restrict__ w8b,
                          const float* __restrict__ sclf, const float* __restrict__ sclb,
                          const int* __restrict__ seq, float* __restrict__ h_ws,
                          const float* __restrict__ x2,
                          const u16* __restrict__ wqb, const float* __restrict__ bq,
                          const u16* __restrict__ wkb, const float* __restrict__ bk,
                          float* __restrict__ pooled){
  __shared__ __align__(16) char smem[159232];        // 2 x 79,616 pooling halves
  const int tid = threadIdx.x;
  const int bid = blockIdx.x;

  if (bid < 16){
    // ============ LSTM path: 6 reg pairs + 4 LDS pool pairs; uses first 37KB ============
    __builtin_amdgcn_s_setprio(2);                   // protect recurrence critical path
    const int lane = tid & 63, wv = tid >> 6;
    const int q = lane & 15, kg = lane >> 4;
    signed char* h8   = (signed char*)smem;          // 4,608
    float* gates      = (float*)(smem + 4608);       // 12,864 -> 17,472
    i32x4* pool       = (i32x4*)(smem + 17472);      // 16,384 -> 33,856
    float* scl_s      = (float*)(smem + 33856);      // 3,200 -> 37,056
    int* Ls           = (int*)(smem + 37056);        // 16 -> 37,072
    const int dir = bid >> 3, grp = bid & 7;
    const u16* xWd = dir ? xWb : xWf;
    const signed char* w8 = dir ? w8b : w8f;
    const float* scl = dir ? sclb : sclf;
    if (tid < 4) Ls[tid] = seq[grp*4 + tid];
    for (int i = tid; i < 1152; i += 512) ((int*)h8)[i] = 0;
    for (int i = tid; i < 800; i += 512) scl_s[i] = scl[i];
    for (int idx = tid; idx < 1024; idx += 512){
      int s = idx >> 8, rem = idx & 255;
      int ksi = rem >> 6, l = rem & 63;
      int qq = l & 15, kk = l >> 4;
      pool[idx] = *(const i32x4*)&w8[(size_t)(3*208 + (9+s)*16 + qq)*256 + ksi*64 + kk*16];
    }
    i32x4 Wr[6][4];
    #pragma unroll
    for (int j = 0; j < 6; j++){
      int p = wv + 8*j, gt = p/13, nt = p - gt*13;
      #pragma unroll
      for (int ksi = 0; ksi < 4; ksi++)
        Wr[j][ksi] = *(const i32x4*)&w8[(size_t)(gt*208 + nt*16 + q)*256 + ksi*64 + kg*16];
    }
    float cst0 = 0.f, cst1 = 0.f;
    const int c0 = tid,        b0c = c0/200, hu0c = c0 - b0c*200;
    const int qd1 = tid + 512;
    const int b1c = qd1/200,   hu1c = qd1 - b1c*200;
    const int xoff0 = ((grp*4 + b0c)*200 + hu0c)*4;
    const int xoff1 = ((grp*4 + b1c)*200 + hu1c)*4;
    short4v xc0 = *(const short4v*)&xWd[xoff0];
    short4v xc1 = {0,0,0,0};
    if (tid < 288) xc1 = *(const short4v*)&xWd[xoff1];
    __syncthreads();
    #pragma unroll 1
    for (int t = 0; t < 256; t++){
      int tn = (t + 1 < 256) ? t + 1 : 255;
      const u16* xwn = xWd + (size_t)tn*25600;
      short4v xn0 = *(const short4v*)&xwn[xoff0];
      short4v xn1 = {0,0,0,0};
      if (tid < 288) xn1 = *(const short4v*)&xwn[xoff1];
      i32x4 bh[4];
      #pragma unroll
      for (int ksi = 0; ksi < 4; ksi++)
        bh[ksi] = *(const i32x4*)&h8[q*288 + ksi*64 + kg*16];
      #pragma unroll
      for (int j = 0; j < 6; j++){
        i32x4 acc = {0,0,0,0};
        #pragma unroll
        for (int ksi = 0; ksi < 4; ksi++)
          acc = MFMAI8(Wr[j][ksi], bh[ksi], acc, 0,0,0);
        store_gate_f32(wv + 8*j, acc, q, kg, gates, scl_s);
      }
      if (wv < 4){                                   // pool pair p = 48+wv
        i32x4 acc = {0,0,0,0};
        #pragma unroll
        for (int ksi = 0; ksi < 4; ksi++)
          acc = MFMAI8(pool[(wv*4 + ksi)*64 + lane], bh[ksi], acc, 0,0,0);
        store_gate_f32(48 + wv, acc, q, kg, gates, scl_s);
      }
      lds_barrier();
      {
        const f32x4 g4 = *(const f32x4*)&gates[b0c*804 + hu0c*4];
        float gi = g4[0] + bf2f((u16)xc0[0]);
        float gf = g4[1] + bf2f((u16)xc0[1]);
        float gg = g4[2] + bf2f((u16)xc0[2]);
        float go = g4[3] + bf2f((u16)xc0[3]);
        float c = sigm(gf)*cst0 + sigm(gi)*tanh_u(gg);
        cst0 = c;
        float hv = sigm(go)*tanh_u(c);
        h8[b0c*288 + hu0c] = (signed char)__float2int_rn(hv*127.f);
        int gb = grp*4 + b0c;
        if (dir == 0){
          h_ws[((size_t)gb*256 + t)*400 + hu0c] = hv;
        } else {
          int tp = Ls[b0c] - 1 - t;
          if (tp >= 0) h_ws[((size_t)gb*256 + tp)*400 + 200 + hu0c] = hv;
        }
      }
      if (tid < 288){
        const f32x4 g4 = *(const f32x4*)&gates[b1c*804 + hu1c*4];
        float gi = g4[0] + bf2f((u16)xc1[0]);
        float gf = g4[1] + bf2f((u16)xc1[1]);
        float gg = g4[2] + bf2f((u16)xc1[2]);
        float go = g4[3] + bf2f((u16)xc1[3]);
        float c = sigm(gf)*cst1 + sigm(gi)*tanh_u(gg);
        cst1 = c;
        float hv = sigm(go)*tanh_u(c);
        h8[b1c*288 + hu1c] = (signed char)__float2int_rn(hv*127.f);
        int gb = grp*4 + b1c;
        if (dir == 0){
          h_ws[((size_t)gb*256 + t)*400 + hu1c] = hv;
        } else {
          int tp = Ls[b1c] - 1 - t;
          if (tp >= 0) h_ws[((size_t)gb*256 + tp)*400 + 200 + hu1c] = hv;
        }
      }
      lds_barrier();
      xc0 = xn0; xc1 = xn1;
    }
  } else {
    // ============ pooling path: two independent r13-style 256-thread halves ============
    const int htid = tid & 255;              // local tid within half
    const int hf   = tid >> 8;               // half index 0/1
    char* hs = smem + hf*79616;
    u16* tok0  = (u16*)hs;                   // [2][6400] 25,600
    u16* qsb   = (u16*)(hs + 25600);         // [2][16*404] 25,856 -> 51,456
    u16* ksb   = (u16*)(hs + 51456);         // 25,856 -> 77,312
    float* msum= (float*)(hs + 77312);       // [2][256] 2,048 -> 79,360
    float* tval= (float*)(hs + 79360);       // 128
    float* attw= (float*)(hs + 79488);       // 128 -> 79,616
    const int lane = htid & 63, wv = htid >> 6;   // wv 0..3 (waves never span halves)
    const int q = lane & 15, kg = lane >> 4;
    const int kb = bid - 16;
    const size_t n0 = (size_t)kb*4 + hf*2;
    const float* src = x2 + n0*6400;
    for (int i = htid; i < 512; i += 256) ((float*)msum)[i] = 0.f;
    for (int i = htid; i < 3200; i += 256){
      f32x4 v = *(const f32x4*)&src[(size_t)i*4];
      short4v s; s[0]=f2bf(v[0]); s[1]=f2bf(v[1]); s[2]=f2bf(v[2]); s[3]=f2bf(v[3]);
      int j = i / 1600, r = i - j*1600;
      ((short4v*)(tok0 + j*6400))[r] = s;
    }
    __syncthreads();
    {
      const int proj = wv >> 1;              // waves 0-1: q, 2-3: k
      const int ntbase = (wv & 1) ? 13 : 0;
      const int ntcnt  = (wv & 1) ? 12 : 13; // 25 col-tiles total
      const u16* W    = proj ? wkb : wqb;
      const float* bias = proj ? bk : bq;
      short8v A[2][13];
      #pragma unroll
      for (int j = 0; j < 2; j++)
        #pragma unroll
        for (int ksi = 0; ksi < 13; ksi++){
          int e0 = ksi*32 + kg*8;
          A[j][ksi] = (e0 < 400) ? *(const short8v*)&tok0[j*6400 + q*400 + e0] : szero();
        }
      u16* d0 = (proj ? ksb : qsb);
      u16* d1 = d0 + 6464;
      for (int ti = 0; ti < ntcnt; ti++){
        int col = (ntbase + ti)*16 + q;
        float bv = bias[col];
        f32x4 acc0, acc1;
        acc0[0]=bv; acc0[1]=bv; acc0[2]=bv; acc0[3]=bv; acc1 = acc0;
        const u16* wrow = W + (size_t)col*400;
        #pragma unroll
        for (int ksi = 0; ksi < 13; ksi++){
          int e0 = ksi*32 + kg*8;
          short8v bf = (e0 < 400) ? *(const short8v*)&wrow[e0] : szero();
          acc0 = MFMA16(A[0][ksi], bf, acc0, 0, 0, 0);
          acc1 = MFMA16(A[1][ksi], bf, acc1, 0, 0, 0);
        }
        #pragma unroll
        for (int r = 0; r < 4; r++){         // D: row=(l>>4)*4+r, col=l&15
          d0[(kg*4+r)*404 + col] = f2bf(acc0[r]);
          d1[(kg*4+r)*404 + col] = f2bf(acc1[r]);
        }
      }
    }
    __syncthreads();
    // score rows (j,hh,sq): lanes 0-15 share (j,hh) -> k reads broadcast
    for (int rr = 0; rr < 3; rr++){
      int row = htid + rr*256;
      if (row < 640){
        int j = row / 320, r2 = row - j*320;
        int hh = r2 >> 4, sq = r2 & 15;
        const u16* qrow = qsb + j*6464 + sq*404 + hh*20;
        float qv[20];
        #pragma unroll
        for (int d5 = 0; d5 < 5; d5++){
          short4v v = *(const short4v*)&qrow[d5*4];
          qv[d5*4+0]=bf2f((u16)v[0]); qv[d5*4+1]=bf2f((u16)v[1]);
          qv[d5*4+2]=bf2f((u16)v[2]); qv[d5*4+3]=bf2f((u16)v[3]);
        }
        float sc[16]; float mx = -1e30f;
        const u16* kbase = ksb + j*6464 + hh*20;
        #pragma unroll
        for (int sk = 0; sk < 16; sk++){
          const u16* krow = kbase + sk*404;
          float s = 0.f;
          #pragma unroll
          for (int d5 = 0; d5 < 5; d5++){
            short4v v = *(const short4v*)&krow[d5*4];
            s += qv[d5*4+0]*bf2f((u16)v[0]) + qv[d5*4+1]*bf2f((u16)v[1])
               + qv[d5*4+2]*bf2f((u16)v[2]) + qv[d5*4+3]*bf2f((u16)v[3]);
          }
          s *= 0.22360679775f;               // 1/sqrt(20)
          sc[sk] = s; mx = fmaxf(mx, s);
        }
        float sum = 0.f;
        #pragma unroll
        for (int sk = 0; sk < 16; sk++){ sc[sk] = __expf(sc[sk]-mx); sum += sc[sk]; }
        float inv = 0.05f/sum;               // fold the 1/20 head-mean in
        #pragma unroll
        for (int sk = 0; sk < 16; sk++){
          float v = sc[sk]*inv;
          v += __shfl_xor(v, 16, 64);        // sum the wave's 4 hh values
          v += __shfl_xor(v, 32, 64);
          if (kg == 0) atomicAdd(&msum[j*256 + sq*16 + sk], v);
        }
      }
    }
    __syncthreads();
    if (htid < 32){                          // mean over sk
      int j = htid >> 4, sq = htid & 15;
      float s = 0.f;
      #pragma unroll
      for (int sk = 0; sk < 16; sk++) s += msum[j*256 + sq*16+sk];
      tval[j*16 + sq] = s * 0.0625f;
    }
    __syncthreads();
    if (htid < 2){                           // softmax over sq (16 values)
      float mx = -1e30f;
      for (int i = 0; i < 16; i++) mx = fmaxf(mx, tval[htid*16+i]);
      float sum = 0.f; float ev[16];
      for (int i = 0; i < 16; i++){ ev[i] = __expf(tval[htid*16+i]-mx); sum += ev[i]; }
      float inv = 1.f/sum;
      for (int i = 0; i < 16; i++) attw[htid*16+i] = ev[i]*inv;
    }
    __syncthreads();
    for (int e = htid; e < 800; e += 256){
      int j = e / 400, c = e - j*400;
      float acc = 0.f;
      #pragma unroll
      for (int s = 0; s < 16; s++) acc += attw[j*16+s]*bf2f(tok0[j*6400 + s*400 + c]);
      pooled[(n0+j)*400 + c] = acc;
    }
  }
}

// ---------------- K2: x2p = pooled @ w_mlp_mha^T + b (f32 VALU) ----------------
__global__ void k2_x2p(const float* __restrict__ pooled, const float* __restrict__ wmha,
                       const float* __restrict__ bmha, float* __restrict__ x2p){
  __shared__ float rows[3200];
  const int tid = threadIdx.x;
  const size_t n0 = (size_t)blockIdx.x*8;
  for (int i = tid; i < 3200; i += 256) rows[i] = pooled[n0*400 + i];
  __syncthreads();
  for (int j = tid; j < 400; j += 256){
    float bv = bmha[j];
    float acc[8];
    #pragma unroll
    for (int r = 0; r < 8; r++) acc[r] = bv;
    const float* wr = wmha + (size_t)j*400;
    for (int e = 0; e < 400; e += 4){
      const f32x4 w4 = *(const f32x4*)&wr[e];
      #pragma unroll
      for (int r = 0; r < 8; r++){
        const f32x4 x4 = *(const f32x4*)&rows[r*400 + e];
        acc[r] += x4[0]*w4[0] + x4[1]*w4[1] + x4[2]*w4[2] + x4[3]*w4[3];
      }
    }
    #pragma unroll
    for (int r = 0; r < 8; r++) x2p[(n0+r)*400 + j] = acc[r];
  }
}

// ---------------- K4b: fill bwd rows t>=L AND compute a[b][t] + per-b max ----------------
__global__ void k4b_fill(const int* __restrict__ seq, float* __restrict__ h_ws,
                         const float* __restrict__ wattn,
                         float* __restrict__ a_ws, float* __restrict__ amax_ws){
  __shared__ float a_lds[256];
  const int b = blockIdx.x;
  const int tid = threadIdx.x;
  const int lane = tid & 63, wv = tid >> 6;
  const int L = seq[b];
  const int cnt = (256 - L)*200;
  const float* srcf = h_ws + ((size_t)b*256 + (L-1))*400 + 200;
  for (int i = tid; i < cnt; i += 256){
    int tt = L + i/200, cc = i - (i/200)*200;
    h_ws[((size_t)b*256 + tt)*400 + 200 + cc] = srcf[cc];
  }
  __syncthreads();
  for (int row = wv*64; row < wv*64 + 64; row++){
    float s = 0.f;
    for (int j = lane; j < 400; j += 64)
      s += h_ws[((size_t)b*256 + row)*400 + j] * wattn[j];
    #pragma unroll
    for (int m = 32; m > 0; m >>= 1) s += __shfl_xor(s, m, 64);
    if (lane == 0) a_lds[row] = s;
  }
  __syncthreads();
  a_ws[b*256 + tid] = a_lds[tid];
  if (tid < 64){
    float m = fmaxf(fmaxf(a_lds[tid], a_lds[tid+64]), fmaxf(a_lds[tid+128], a_lds[tid+192]));
    #pragma unroll
    for (int mm = 32; mm > 0; mm >>= 1) m = fmaxf(m, __shfl_xor(m, mm, 64));
    if (tid == 0) amax_ws[b] = m;
  }
}

// ---------------- K5: causal attention as exact cumsum (const per-b max). grid 256. ----------------
__launch_bounds__(256)
__global__ void k5_attn(const float* __restrict__ h_ws, const float* __restrict__ a_ws,
                        const float* __restrict__ amax_ws, float* __restrict__ x1_att){
  __shared__ float tile[256*52];       // [t][col-chunk 50, pad 52], in-place h -> out
  __shared__ float wl[256];
  const int tid = threadIdx.x;
  const int b = blockIdx.x >> 3, ch = blockIdx.x & 7;
  const int c0 = ch*50;
  wl[tid] = __expf(a_ws[b*256 + tid] - amax_ws[b]);
  for (int i = tid; i < 12800; i += 256){
    int r = i / 50, c = i - r*50;
    tile[r*52 + c] = h_ws[((size_t)b*256 + r)*400 + c0 + c];
  }
  __syncthreads();
  if (tid < 50){
    float den = 0.f, num = 0.f;
    #pragma unroll 4
    for (int t = 0; t < 256; t++){
      float w = wl[t];
      den += w;
      num += w * tile[t*52 + tid];
      tile[t*52 + tid] = num/den;
    }
  }
  __syncthreads();
  for (int i = tid; i < 12800; i += 256){
    int r = i / 50, c = i - r*50;
    x1_att[((size_t)b*256 + r)*400 + c0 + c] = tile[r*52 + c];
  }
}

// ---------------- K6: out = [x1_att ; x2p] @ w_mlp^T + b, masked, f32 ----------------
__global__ void k6_out(const float* __restrict__ x1_att, const float* __restrict__ x2p,
                       const float* __restrict__ wmlp, const float* __restrict__ bmlp,
                       const int* __restrict__ seq, float* __restrict__ out){
  __shared__ float rows[8*800];
  const int tid = threadIdx.x;
  const size_t n0 = (size_t)blockIdx.x*8;
  const int b = (int)(n0 >> 8), t0 = (int)(n0 & 255);
  const int L = seq[b];
  for (int i = tid; i < 3200; i += 256){
    int r = i / 400, e = i - r*400;
    rows[r*800 + e]       = x1_att[(n0 + r)*400 + e];
    rows[r*800 + 400 + e] = x2p  [(n0 + r)*400 + e];
  }
  __syncthreads();
  for (int e = tid; e < 400; e += 256){
    float bv = bmlp[e];
    float acc[8];
    #pragma unroll
    for (int r = 0; r < 8; r++) acc[r] = bv;
    const float* wr = wmlp + (size_t)e*800;
    for (int j = 0; j < 800; j += 4){
      const f32x4 w4 = *(const f32x4*)&wr[j];
      #pragma unroll
      for (int r = 0; r < 8; r++){
        const f32x4 x4 = *(const f32x4*)&rows[r*800 + j];
        acc[r] += x4[0]*w4[0] + x4[1]*w4[1] + x4[2]*w4[2] + x4[3]*w4[3];
      }
    }
    #pragma unroll
    for (int r = 0; r < 8; r++){
      float v = (t0 + r < L) ? acc[r] : 0.f;
      out[(n0 + r)*400 + e] = v;
    }
  }
}

extern "C" void kernel_launch(void* const* d_in, const int* in_sizes, int n_in,
                              void* d_out, int out_size, void* d_ws, size_t ws_size,
                              hipStream_t stream){
  const float* x1   = (const float*)d_in[0];
  const float* x2   = (const float*)d_in[1];
  // d_in[2] = cate: unused by the reference
  const int*   seq  = (const int*)d_in[3];
  const float* wihf = (const float*)d_in[4];
  const float* whhf = (const float*)d_in[5];
  const float* bihf = (const float*)d_in[6];
  const float* bhhf = (const float*)d_in[7];
  const float* wihb = (const float*)d_in[8];
  const float* whhb = (const float*)d_in[9];
  const float* bihb = (const float*)d_in[10];
  const float* bhhb = (const float*)d_in[11];
  const float* wq   = (const float*)d_in[12];
  const float* bq   = (const float*)d_in[13];
  const float* wk   = (const float*)d_in[14];
  const float* bk   = (const float*)d_in[15];
  const float* wmha = (const float*)d_in[16];
  const float* bmha = (const float*)d_in[17];
  const float* wattn= (const float*)d_in[18];
  // d_in[19] = b_attn: cancels in softmax
  const float* wmlp = (const float*)d_in[20];
  const float* bmlp = (const float*)d_in[21];
  float* out = (float*)d_out;

  char* ws = (char*)d_ws;
  u16*  wqb    = (u16*)(ws + 0);              // 320,000 B
  u16*  wkb    = (u16*)(ws + 320000);         // 320,000
  u16*  wihfb  = (u16*)(ws + 640000);         // 640,000
  u16*  wihbb  = (u16*)(ws + 1280000);        // 640,000
  signed char* w8f  = (signed char*)(ws + 1920000);  // 212,992
  signed char* w8b  = (signed char*)(ws + 2132992);  // 212,992
  float* sclf  = (float*)(ws + 2345984);      // 3,200
  float* sclb  = (float*)(ws + 2349184);      // 3,200
  float* bgf   = (float*)(ws + 2352384);      // 3,200
  float* bgb   = (float*)(ws + 2355584);      // 3,200 -> end 2,358,784
  float* pooled= (float*)(ws + 2359296);      // 13,107,200
  float* x2p   = (float*)(ws + 15466496);     // 13,107,200
  u16*  xWf    = (u16*)(ws + 28573696);       // 13,107,200
  u16*  xWb    = (u16*)(ws + 41680896);       // 13,107,200
  float* h_ws  = (float*)(ws + 54788096);     // 13,107,200 -> end 67,895,296
  float* a_ws  = (float*)(ws + 67895296);     // 32,768
  float* amax_ws=(float*)(ws + 67928064);     // 128 (end ~67.93MB)
  float* x1_att= (float*)(ws + 28573696);     // overlay: xWf dead after k41

  k0_cvt  <<<dim3(1250), dim3(256), 0, stream>>>(wq, wk, wihf, wihb,
                                                 bihf, bhhf, bihb, bhhb,
                                                 wqb, wkb, wihfb, wihbb, bgf, bgb);
  k0b_quant<<<dim3(416), dim3(256), 0, stream>>>(whhf, whhb, w8f, w8b, sclf, sclb);
  k3_xw   <<<dim3(256),  dim3(512), 0, stream>>>(x1, seq, wihfb, wihbb, bgf, bgb, xWf, xWb);
  k41_fused<<<dim3(2064), dim3(512), 0, stream>>>(xWf, xWb, w8f, w8b, sclf, sclb, seq, h_ws,
                                                  x2, wqb, bq, wkb, bk, pooled);
  k2_x2p  <<<dim3(1024), dim3(256), 0, stream>>>(pooled, wmha, bmha, x2p);
  k4b_fill<<<dim3(32),   dim3(256), 0, stream>>>(seq, h_ws, wattn, a_ws, amax_ws);
  k5_attn <<<dim3(256),  dim3(256), 0, stream>>>(h_ws, a_ws, amax_ws, x1_att);
  k6_out  <<<dim3(1024), dim3(256), 0, stream>>>(x1_att, x2p, wmlp, bmlp, seq, out);
}

// Round 19
// 818.024 us; speedup vs baseline: 1.5066x; 1.1690x over previous
//
// NeRTModel_60997125538302 — round 19: MFMA-ize k6 (the largest tail kernel).
// r18 win confirmed (fused 513us, total 956): pooling as 2x256-thr halves fixed the
// block-shape convoy. Tail = ~443us; FLOP accounting says k6 (10.5 GFLOP f32 VALU,
// ~120-150us) dominates. New k6: stage 32 rows x 800 concat(x1_att,x2p) bf16 in LDS,
// 8 waves x ~3 col-tiles, per-ksi A ds_read_b128 + global B (wmlpb bf16, L2-resident),
// f32 acc, masked store. k0 also converts wmlp->bf16. k2 stays f32 (bounds accuracy).
// Everything else identical to round 18.

#include <hip/hip_runtime.h>
#include <hip/hip_bf16.h>
#include <cstdint>
#include <cstddef>

typedef unsigned short u16;
typedef __attribute__((ext_vector_type(8))) short short8v;
typedef __attribute__((ext_vector_type(4))) short short4v;
typedef __attribute__((ext_vector_type(4))) float f32x4;
typedef __attribute__((ext_vector_type(4))) int i32x4;

#define MFMA16 __builtin_amdgcn_mfma_f32_16x16x32_bf16
#define MFMAI8 __builtin_amdgcn_mfma_i32_16x16x64_i8

__device__ __forceinline__ float bf2f(u16 u){
  union { unsigned int i; float f; } v; v.i = ((unsigned int)u) << 16; return v.f;
}
__device__ __forceinline__ u16 f2bf(float f){
  union { float f; unsigned int u; } v; v.f = f;
  unsigned int r = v.u + 0x7FFFu + ((v.u >> 16) & 1u);
  return (u16)(r >> 16);
}
__device__ __forceinline__ short8v szero(){
  short8v z;
  #pragma unroll
  for (int i = 0; i < 8; i++) z[i] = 0;
  return z;
}
__device__ __forceinline__ float sigm(float x){ return 1.0f/(1.0f + __expf(-x)); }
__device__ __forceinline__ float tanh_u(float x){
  float e = __expf(2.f*x);              // overflow -> inf -> tanh -> 1 (no NaN)
  return 1.f - 2.f/(e + 1.f);
}
// LDS-visibility-only barrier: does NOT drain vmcnt.
__device__ __forceinline__ void lds_barrier(){
  asm volatile("s_waitcnt lgkmcnt(0)" ::: "memory");
  __builtin_amdgcn_s_barrier();
  __builtin_amdgcn_sched_barrier(0);
}

// ---------------- K0: convert non-recurrent weights f32 -> bf16; fuse LSTM biases ----------------
__global__ void k0_cvt(const float* __restrict__ wq, const float* __restrict__ wk,
                       const float* __restrict__ wihf, const float* __restrict__ wihb,
                       const float* __restrict__ wmlp,
                       const float* __restrict__ bihf, const float* __restrict__ bhhf,
                       const float* __restrict__ bihb, const float* __restrict__ bhhb,
                       u16* __restrict__ wqb, u16* __restrict__ wkb,
                       u16* __restrict__ wihfb, u16* __restrict__ wihbb,
                       u16* __restrict__ wmlpb,
                       float* __restrict__ bgf, float* __restrict__ bgb){
  int i = blockIdx.x*256 + threadIdx.x;
  if (i < 160000){ wqb[i] = f2bf(wq[i]); wkb[i] = f2bf(wk[i]); }
  if (i < 320000){ wihfb[i] = f2bf(wihf[i]); wihbb[i] = f2bf(wihb[i]); wmlpb[i] = f2bf(wmlp[i]); }
  if (i < 800){ bgf[i] = bihf[i] + bhhf[i]; bgb[i] = bihb[i] + bhhb[i]; }
}

// ---------------- K0b: row-quantize W_hh -> i8 [4 gate][208 row][256 k] + scales ----------------
__global__ void k0b_quant(const float* __restrict__ whhf, const float* __restrict__ whhb,
                          signed char* __restrict__ w8f, signed char* __restrict__ w8b,
                          float* __restrict__ sclf, float* __restrict__ sclb){
  const int tid = threadIdx.x, lane = tid & 63, wv = tid >> 6;
  const int widx = blockIdx.x*4 + wv;              // 0..1663
  if (widx < 1600){
    int dir = widx / 800, g = widx - dir*800;
    const float* src = (dir ? whhb : whhf) + (size_t)g*200;
    float mx = 0.f;
    for (int j = lane; j < 200; j += 64) mx = fmaxf(mx, fabsf(src[j]));
    #pragma unroll
    for (int m = 32; m > 0; m >>= 1) mx = fmaxf(mx, __shfl_xor(mx, m, 64));
    float inv = (mx > 0.f) ? 127.f/mx : 0.f;
    int gt = g / 200, hl = g - gt*200;
    signed char* dst = (dir ? w8b : w8f) + (size_t)(gt*208 + hl)*256;
    int e0 = lane*4;
    unsigned int pack = 0u;
    if (e0 < 200){
      #pragma unroll
      for (int r = 0; r < 4; r++){
        int qv = __float2int_rn(src[e0+r]*inv);
        pack |= ((unsigned int)(qv & 255)) << (8*r);
      }
    }
    ((unsigned int*)dst)[lane] = pack;               // lanes 50..63 zero the k-pad
    if (lane == 0) (dir ? sclb : sclf)[g] = mx / 16129.f;   // mx / 127^2
  } else {
    int pr = widx - 1600;                            // 64 pad rows
    int dir = pr >> 5, rem = pr & 31, gt = rem >> 3, hl = 200 + (rem & 7);
    signed char* dst = (dir ? w8b : w8f) + (size_t)(gt*208 + hl)*256;
    ((unsigned int*)dst)[lane] = 0u;
  }
}

// ---------------- K3: xW = x @ W_ih^T + (b_ih+b_hh), layout [t][b32][hu][gt] bf16 ----------------
__launch_bounds__(512)
__global__ void k3_xw(const float* __restrict__ x1, const int* __restrict__ seq,
                      const u16* __restrict__ wihfb, const u16* __restrict__ wihbb,
                      const float* __restrict__ bgf, const float* __restrict__ bgb,
                      u16* __restrict__ xWf, u16* __restrict__ xWb){
  __shared__ u16 xf[12800];
  __shared__ u16 xb[12800];
  const int tid = threadIdx.x;
  const int t = blockIdx.x;
  for (int i = tid; i < 3200; i += 512){
    int b = i / 100, e4 = i - b*100;
    f32x4 vf = *(const f32x4*)&x1[((size_t)b*256 + t)*400 + e4*4];
    int rb = seq[b] - 1 - t; if (rb < 0) rb = 0;     // clip(L-1-t, 0, T-1)
    f32x4 vb = *(const f32x4*)&x1[((size_t)b*256 + rb)*400 + e4*4];
    short4v sf, sb;
    #pragma unroll
    for (int r = 0; r < 4; r++){ sf[r] = f2bf(vf[r]); sb[r] = f2bf(vb[r]); }
    ((short4v*)xf)[i] = sf;
    ((short4v*)xb)[i] = sb;
  }
  __syncthreads();
  const int lane = tid & 63, wv = tid >> 6;
  const int dir = wv >> 2, wl = wv & 3;
  const u16* xs = dir ? xb : xf;
  const u16* W  = dir ? wihbb : wihfb;
  const float* bg = dir ? bgb : bgf;
  u16* xW = dir ? xWb : xWf;
  const int q = lane & 15, kg = lane >> 4;
  short8v A[2][13];
  #pragma unroll
  for (int mt = 0; mt < 2; mt++)
    #pragma unroll
    for (int ksi = 0; ksi < 13; ksi++){
      int e0 = ksi*32 + kg*8;
      A[mt][ksi] = (e0 < 400) ? *(const short8v*)&xs[(mt*16 + q)*400 + e0] : szero();
    }
  for (int nt = wl; nt < 50; nt += 4){
    int g = nt*16 + q;                       // gate row 0..799
    float bv = bg[g];
    f32x4 acc0, acc1;
    acc0[0]=bv; acc0[1]=bv; acc0[2]=bv; acc0[3]=bv; acc1 = acc0;
    const u16* wrow = W + (size_t)g*400;
    #pragma unroll
    for (int ksi = 0; ksi < 13; ksi++){
      int e0 = ksi*32 + kg*8;
      short8v bf = (e0 < 400) ? *(const short8v*)&wrow[e0] : szero();
      acc0 = MFMA16(A[0][ksi], bf, acc0, 0,0,0);
      acc1 = MFMA16(A[1][ksi], bf, acc1, 0,0,0);
    }
    int gt = g / 200, hu = g - gt*200;
    #pragma unroll
    for (int r = 0; r < 4; r++){
      int bl = kg*4 + r;                     // D rows = batch rows
      xW[(((size_t)t*32 +      bl)*200 + hu)*4 + gt] = f2bf(acc0[r]);
      xW[(((size_t)t*32 + 16 + bl)*200 + hu)*4 + gt] = f2bf(acc1[r]);
    }
  }
}

// ---------------- K41: FUSED LSTM (blocks 0-15) + pooling (blocks 16+, 2x256-thr halves). ----------------
__device__ __forceinline__ void store_gate_f32(int p, const i32x4& acc, int q, int kg,
                                               float* gates, const float* scl_s){
  int gt = p/13, nt = p - gt*13;
  int hu0 = nt*16 + kg*4;
  if (hu0 < 200 && q < 4){
    const f32x4 s4 = *(const f32x4*)&scl_s[gt*200 + hu0];
    #pragma unroll
    for (int r = 0; r < 4; r++)
      gates[q*804 + (hu0+r)*4 + gt] = (float)acc[r]*s4[r];
  }
}

__launch_bounds__(512)
__global__ void k41_fused(const u16* __restrict__ xWf, const u16* __restrict__ xWb,
                          const signed char* __restrict__ w8f, const signed char* __restrict__ w8b,
                          const float* __restrict__ sclf, const float* __restrict__ sclb,
                          const int* __restrict__ seq, float* __restrict__ h_ws,
                          const float* __restrict__ x2,
                          const u16* __restrict__ wqb, const float* __restrict__ bq,
                          const u16* __restrict__ wkb, const float* __restrict__ bk,
                          float* __restrict__ pooled){
  __shared__ __align__(16) char smem[159232];        // 2 x 79,616 pooling halves
  const int tid = threadIdx.x;
  const int bid = blockIdx.x;

  if (bid < 16){
    // ============ LSTM path: 6 reg pairs + 4 LDS pool pairs; uses first 37KB ============
    __builtin_amdgcn_s_setprio(2);                   // protect recurrence critical path
    const int lane = tid & 63, wv = tid >> 6;
    const int q = lane & 15, kg = lane >> 4;
    signed char* h8   = (signed char*)smem;          // 4,608
    float* gates      = (float*)(smem + 4608);       // 12,864 -> 17,472
    i32x4* pool       = (i32x4*)(smem + 17472);      // 16,384 -> 33,856
    float* scl_s      = (float*)(smem + 33856);      // 3,200 -> 37,056
    int* Ls           = (int*)(smem + 37056);        // 16 -> 37,072
    const int dir = bid >> 3, grp = bid & 7;
    const u16* xWd = dir ? xWb : xWf;
    const signed char* w8 = dir ? w8b : w8f;
    const float* scl = dir ? sclb : sclf;
    if (tid < 4) Ls[tid] = seq[grp*4 + tid];
    for (int i = tid; i < 1152; i += 512) ((int*)h8)[i] = 0;
    for (int i = tid; i < 800; i += 512) scl_s[i] = scl[i];
    for (int idx = tid; idx < 1024; idx += 512){
      int s = idx >> 8, rem = idx & 255;
      int ksi = rem >> 6, l = rem & 63;
      int qq = l & 15, kk = l >> 4;
      pool[idx] = *(const i32x4*)&w8[(size_t)(3*208 + (9+s)*16 + qq)*256 + ksi*64 + kk*16];
    }
    i32x4 Wr[6][4];
    #pragma unroll
    for (int j = 0; j < 6; j++){
      int p = wv + 8*j, gt = p/13, nt = p - gt*13;
      #pragma unroll
      for (int ksi = 0; ksi < 4; ksi++)
        Wr[j][ksi] = *(const i32x4*)&w8[(size_t)(gt*208 + nt*16 + q)*256 + ksi*64 + kg*16];
    }
    float cst0 = 0.f, cst1 = 0.f;
    const int c0 = tid,        b0c = c0/200, hu0c = c0 - b0c*200;
    const int qd1 = tid + 512;
    const int b1c = qd1/200,   hu1c = qd1 - b1c*200;
    const int xoff0 = ((grp*4 + b0c)*200 + hu0c)*4;
    const int xoff1 = ((grp*4 + b1c)*200 + hu1c)*4;
    short4v xc0 = *(const short4v*)&xWd[xoff0];
    short4v xc1 = {0,0,0,0};
    if (tid < 288) xc1 = *(const short4v*)&xWd[xoff1];
    __syncthreads();
    #pragma unroll 1
    for (int t = 0; t < 256; t++){
      int tn = (t + 1 < 256) ? t + 1 : 255;
      const u16* xwn = xWd + (size_t)tn*25600;
      short4v xn0 = *(const short4v*)&xwn[xoff0];
      short4v xn1 = {0,0,0,0};
      if (tid < 288) xn1 = *(const short4v*)&xwn[xoff1];
      i32x4 bh[4];
      #pragma unroll
      for (int ksi = 0; ksi < 4; ksi++)
        bh[ksi] = *(const i32x4*)&h8[q*288 + ksi*64 + kg*16];
      #pragma unroll
      for (int j = 0; j < 6; j++){
        i32x4 acc = {0,0,0,0};
        #pragma unroll
        for (int ksi = 0; ksi < 4; ksi++)
          acc = MFMAI8(Wr[j][ksi], bh[ksi], acc, 0,0,0);
        store_gate_f32(wv + 8*j, acc, q, kg, gates, scl_s);
      }
      if (wv < 4){                                   // pool pair p = 48+wv
        i32x4 acc = {0,0,0,0};
        #pragma unroll
        for (int ksi = 0; ksi < 4; ksi++)
          acc = MFMAI8(pool[(wv*4 + ksi)*64 + lane], bh[ksi], acc, 0,0,0);
        store_gate_f32(48 + wv, acc, q, kg, gates, scl_s);
      }
      lds_barrier();
      {
        const f32x4 g4 = *(const f32x4*)&gates[b0c*804 + hu0c*4];
        float gi = g4[0] + bf2f((u16)xc0[0]);
        float gf = g4[1] + bf2f((u16)xc0[1]);
        float gg = g4[2] + bf2f((u16)xc0[2]);
        float go = g4[3] + bf2f((u16)xc0[3]);
        float c = sigm(gf)*cst0 + sigm(gi)*tanh_u(gg);
        cst0 = c;
        float hv = sigm(go)*tanh_u(c);
        h8[b0c*288 + hu0c] = (signed char)__float2int_rn(hv*127.f);
        int gb = grp*4 + b0c;
        if (dir == 0){
          h_ws[((size_t)gb*256 + t)*400 + hu0c] = hv;
        } else {
          int tp = Ls[b0c] - 1 - t;
          if (tp >= 0) h_ws[((size_t)gb*256 + tp)*400 + 200 + hu0c] = hv;
        }
      }
      if (tid < 288){
        const f32x4 g4 = *(const f32x4*)&gates[b1c*804 + hu1c*4];
        float gi = g4[0] + bf2f((u16)xc1[0]);
        float gf = g4[1] + bf2f((u16)xc1[1]);
        float gg = g4[2] + bf2f((u16)xc1[2]);
        float go = g4[3] + bf2f((u16)xc1[3]);
        float c = sigm(gf)*cst1 + sigm(gi)*tanh_u(gg);
        cst1 = c;
        float hv = sigm(go)*tanh_u(c);
        h8[b1c*288 + hu1c] = (signed char)__float2int_rn(hv*127.f);
        int gb = grp*4 + b1c;
        if (dir == 0){
          h_ws[((size_t)gb*256 + t)*400 + hu1c] = hv;
        } else {
          int tp = Ls[b1c] - 1 - t;
          if (tp >= 0) h_ws[((size_t)gb*256 + tp)*400 + 200 + hu1c] = hv;
        }
      }
      lds_barrier();
      xc0 = xn0; xc1 = xn1;
    }
  } else {
    // ============ pooling path: two independent r13-style 256-thread halves ============
    const int htid = tid & 255;              // local tid within half
    const int hf   = tid >> 8;               // half index 0/1
    char* hs = smem + hf*79616;
    u16* tok0  = (u16*)hs;                   // [2][6400] 25,600
    u16* qsb   = (u16*)(hs + 25600);         // [2][16*404] 25,856 -> 51,456
    u16* ksb   = (u16*)(hs + 51456);         // 25,856 -> 77,312
    float* msum= (float*)(hs + 77312);       // [2][256] 2,048 -> 79,360
    float* tval= (float*)(hs + 79360);       // 128
    float* attw= (float*)(hs + 79488);       // 128 -> 79,616
    const int lane = htid & 63, wv = htid >> 6;   // wv 0..3 (waves never span halves)
    const int q = lane & 15, kg = lane >> 4;
    const int kb = bid - 16;
    const size_t n0 = (size_t)kb*4 + hf*2;
    const float* src = x2 + n0*6400;
    for (int i = htid; i < 512; i += 256) ((float*)msum)[i] = 0.f;
    for (int i = htid; i < 3200; i += 256){
      f32x4 v = *(const f32x4*)&src[(size_t)i*4];
      short4v s; s[0]=f2bf(v[0]); s[1]=f2bf(v[1]); s[2]=f2bf(v[2]); s[3]=f2bf(v[3]);
      int j = i / 1600, r = i - j*1600;
      ((short4v*)(tok0 + j*6400))[r] = s;
    }
    __syncthreads();
    {
      const int proj = wv >> 1;              // waves 0-1: q, 2-3: k
      const int ntbase = (wv & 1) ? 13 : 0;
      const int ntcnt  = (wv & 1) ? 12 : 13; // 25 col-tiles total
      const u16* W    = proj ? wkb : wqb;
      const float* bias = proj ? bk : bq;
      short8v A[2][13];
      #pragma unroll
      for (int j = 0; j < 2; j++)
        #pragma unroll
        for (int ksi = 0; ksi < 13; ksi++){
          int e0 = ksi*32 + kg*8;
          A[j][ksi] = (e0 < 400) ? *(const short8v*)&tok0[j*6400 + q*400 + e0] : szero();
        }
      u16* d0 = (proj ? ksb : qsb);
      u16* d1 = d0 + 6464;
      for (int ti = 0; ti < ntcnt; ti++){
        int col = (ntbase + ti)*16 + q;
        float bv = bias[col];
        f32x4 acc0, acc1;
        acc0[0]=bv; acc0[1]=bv; acc0[2]=bv; acc0[3]=bv; acc1 = acc0;
        const u16* wrow = W + (size_t)col*400;
        #pragma unroll
        for (int ksi = 0; ksi < 13; ksi++){
          int e0 = ksi*32 + kg*8;
          short8v bf = (e0 < 400) ? *(const short8v*)&wrow[e0] : szero();
          acc0 = MFMA16(A[0][ksi], bf, acc0, 0, 0, 0);
          acc1 = MFMA16(A[1][ksi], bf, acc1, 0, 0, 0);
        }
        #pragma unroll
        for (int r = 0; r < 4; r++){         // D: row=(l>>4)*4+r, col=l&15
          d0[(kg*4+r)*404 + col] = f2bf(acc0[r]);
          d1[(kg*4+r)*404 + col] = f2bf(acc1[r]);
        }
      }
    }
    __syncthreads();
    // score rows (j,hh,sq): lanes 0-15 share (j,hh) -> k reads broadcast
    for (int rr = 0; rr < 3; rr++){
      int row = htid + rr*256;
      if (row < 640){
        int j = row / 320, r2 = row - j*320;
        int hh = r2 >> 4, sq = r2 & 15;
        const u16* qrow = qsb + j*6464 + sq*404 + hh*20;
        float qv[20];
        #pragma unroll
        for (int d5 = 0; d5 < 5; d5++){
          short4v v = *(const short4v*)&qrow[d5*4];
          qv[d5*4+0]=bf2f((u16)v[0]); qv[d5*4+1]=bf2f((u16)v[1]);
          qv[d5*4+2]=bf2f((u16)v[2]); qv[d5*4+3]=bf2f((u16)v[3]);
        }
        float sc[16]; float mx = -1e30f;
        const u16* kbase = ksb + j*6464 + hh*20;
        #pragma unroll
        for (int sk = 0; sk < 16; sk++){
          const u16* krow = kbase + sk*404;
          float s = 0.f;
          #pragma unroll
          for (int d5 = 0; d5 < 5; d5++){
            short4v v = *(const short4v*)&krow[d5*4];
            s += qv[d5*4+0]*bf2f((u16)v[0]) + qv[d5*4+1]*bf2f((u16)v[1])
               + qv[d5*4+2]*bf2f((u16)v[2]) + qv[d5*4+3]*bf2f((u16)v[3]);
          }
          s *= 0.22360679775f;               // 1/sqrt(20)
          sc[sk] = s; mx = fmaxf(mx, s);
        }
        float sum = 0.f;
        #pragma unroll
        for (int sk = 0; sk < 16; sk++){ sc[sk] = __expf(sc[sk]-mx); sum += sc[sk]; }
        float inv = 0.05f/sum;               // fold the 1/20 head-mean in
        #pragma unroll
        for (int sk = 0; sk < 16; sk++){
          float v = sc[sk]*inv;
          v += __shfl_xor(v, 16, 64);        // sum the wave's 4 hh values
          v += __shfl_xor(v, 32, 64);
          if (kg == 0) atomicAdd(&msum[j*256 + sq*16 + sk], v);
        }
      }
    }
    __syncthreads();
    if (htid < 32){                          // mean over sk
      int j = htid >> 4, sq = htid & 15;
      float s = 0.f;
      #pragma unroll
      for (int sk = 0; sk < 16; sk++) s += msum[j*256 + sq*16+sk];
      tval[j*16 + sq] = s * 0.0625f;
    }
    __syncthreads();
    if (htid < 2){                           // softmax over sq (16 values)
      float mx = -1e30f;
      for (int i = 0; i < 16; i++) mx = fmaxf(mx, tval[htid*16+i]);
      float sum = 0.f; float ev[16];
      for (int i = 0; i < 16; i++){ ev[i] = __expf(tval[htid*16+i]-mx); sum += ev[i]; }
      float inv = 1.f/sum;
      for (int i = 0; i < 16; i++) attw[htid*16+i] = ev[i]*inv;
    }
    __syncthreads();
    for (int e = htid; e < 800; e += 256){
      int j = e / 400, c = e - j*400;
      float acc = 0.f;
      #pragma unroll
      for (int s = 0; s < 16; s++) acc += attw[j*16+s]*bf2f(tok0[j*6400 + s*400 + c]);
      pooled[(n0+j)*400 + c] = acc;
    }
  }
}

// ---------------- K2: x2p = pooled @ w_mlp_mha^T + b (f32 VALU) ----------------
__global__ void k2_x2p(const float* __restrict__ pooled, const float* __restrict__ wmha,
                       const float* __restrict__ bmha, float* __restrict__ x2p){
  __shared__ float rows[3200];
  const int tid = threadIdx.x;
  const size_t n0 = (size_t)blockIdx.x*8;
  for (int i = tid; i < 3200; i += 256) rows[i] = pooled[n0*400 + i];
  __syncthreads();
  for (int j = tid; j < 400; j += 256){
    float bv = bmha[j];
    float acc[8];
    #pragma unroll
    for (int r = 0; r < 8; r++) acc[r] = bv;
    const float* wr = wmha + (size_t)j*400;
    for (int e = 0; e < 400; e += 4){
      const f32x4 w4 = *(const f32x4*)&wr[e];
      #pragma unroll
      for (int r = 0; r < 8; r++){
        const f32x4 x4 = *(const f32x4*)&rows[r*400 + e];
        acc[r] += x4[0]*w4[0] + x4[1]*w4[1] + x4[2]*w4[2] + x4[3]*w4[3];
      }
    }
    #pragma unroll
    for (int r = 0; r < 8; r++) x2p[(n0+r)*400 + j] = acc[r];
  }
}

// ---------------- K4b: fill bwd rows t>=L AND compute a[b][t] + per-b max ----------------
__global__ void k4b_fill(const int* __restrict__ seq, float* __restrict__ h_ws,
                         const float* __restrict__ wattn,
                         float* __restrict__ a_ws, float* __restrict__ amax_ws){
  __shared__ float a_lds[256];
  const int b = blockIdx.x;
  const int tid = threadIdx.x;
  const int lane = tid & 63, wv = tid >> 6;
  const int L = seq[b];
  const int cnt = (256 - L)*200;
  const float* srcf = h_ws + ((size_t)b*256 + (L-1))*400 + 200;
  for (int i = tid; i < cnt; i += 256){
    int tt = L + i/200, cc = i - (i/200)*200;
    h_ws[((size_t)b*256 + tt)*400 + 200 + cc] = srcf[cc];
  }
  __syncthreads();
  for (int row = wv*64; row < wv*64 + 64; row++){
    float s = 0.f;
    for (int j = lane; j < 400; j += 64)
      s += h_ws[((size_t)b*256 + row)*400 + j] * wattn[j];
    #pragma unroll
    for (int m = 32; m > 0; m >>= 1) s += __shfl_xor(s, m, 64);
    if (lane == 0) a_lds[row] = s;
  }
  __syncthreads();
  a_ws[b*256 + tid] = a_lds[tid];
  if (tid < 64){
    float m = fmaxf(fmaxf(a_lds[tid], a_lds[tid+64]), fmaxf(a_lds[tid+128], a_lds[tid+192]));
    #pragma unroll
    for (int mm = 32; mm > 0; mm >>= 1) m = fmaxf(m, __shfl_xor(m, mm, 64));
    if (tid == 0) amax_ws[b] = m;
  }
}

// ---------------- K5: causal attention as exact cumsum (const per-b max). grid 256. ----------------
__launch_bounds__(256)
__global__ void k5_attn(const float* __restrict__ h_ws, const float* __restrict__ a_ws,
                        const float* __restrict__ amax_ws, float* __restrict__ x1_att){
  __shared__ float tile[256*52];       // [t][col-chunk 50, pad 52], in-place h -> out
  __shared__ float wl[256];
  const int tid = threadIdx.x;
  const int b = blockIdx.x >> 3, ch = blockIdx.x & 7;
  const int c0 = ch*50;
  wl[tid] = __expf(a_ws[b*256 + tid] - amax_ws[b]);
  for (int i = tid; i < 12800; i += 256){
    int r = i / 50, c = i - r*50;
    tile[r*52 + c] = h_ws[((size_t)b*256 + r)*400 + c0 + c];
  }
  __syncthreads();
  if (tid < 50){
    float den = 0.f, num = 0.f;
    #pragma unroll 4
    for (int t = 0; t < 256; t++){
      float w = wl[t];
      den += w;
      num += w * tile[t*52 + tid];
      tile[t*52 + tid] = num/den;
    }
  }
  __syncthreads();
  for (int i = tid; i < 12800; i += 256){
    int r = i / 50, c = i - r*50;
    x1_att[((size_t)b*256 + r)*400 + c0 + c] = tile[r*52 + c];
  }
}

// ---------------- K6: MFMA out = [x1_att ; x2p] @ w_mlp^T + b, masked. grid 256 x 512thr. ----------------
__launch_bounds__(512)
__global__ void k6_out(const float* __restrict__ x1_att, const float* __restrict__ x2p,
                       const u16* __restrict__ wmlpb, const float* __restrict__ bmlp,
                       const int* __restrict__ seq, float* __restrict__ out){
  __shared__ __align__(16) u16 rows[32*800];         // 51,200 B bf16 concat rows
  const int tid = threadIdx.x;
  const size_t n0 = (size_t)blockIdx.x*32;
  const int b = (int)(n0 >> 8), t0 = (int)(n0 & 255);
  const int L = seq[b];
  for (int c = tid; c < 6400; c += 512){             // 32 rows x 800 cols, f32x4 chunks
    int r = c / 200, u = c - r*200;
    const float* sp = (u < 100) ? &x1_att[(n0 + r)*400 + u*4]
                                : &x2p  [(n0 + r)*400 + (u-100)*4];
    f32x4 v = *(const f32x4*)sp;
    int cb = (u < 100) ? u*4 : 400 + (u-100)*4;
    short4v s;
    #pragma unroll
    for (int r2 = 0; r2 < 4; r2++) s[r2] = f2bf(v[r2]);
    *(short4v*)&rows[r*800 + cb] = s;
  }
  __syncthreads();
  const int lane = tid & 63, wv = tid >> 6;
  const int q = lane & 15, kg = lane >> 4;
  const int ntasks = (wv == 0) ? 4 : 3;              // 25 col-tiles over 8 waves
  for (int ti = 0; ti < ntasks; ti++){
    int nt = (ti < 3) ? (wv + ti*8) : 24;
    int col = nt*16 + q;                             // output col 0..399
    float bv = bmlp[col];
    f32x4 acc0, acc1;
    acc0[0]=bv; acc0[1]=bv; acc0[2]=bv; acc0[3]=bv; acc1 = acc0;
    const u16* wrow = wmlpb + (size_t)col*800;
    #pragma unroll
    for (int ksi = 0; ksi < 25; ksi++){
      int e0 = ksi*32 + kg*8;
      short8v bf = *(const short8v*)&wrow[e0];
      short8v a0 = *(const short8v*)&rows[q*800 + e0];
      short8v a1 = *(const short8v*)&rows[(16+q)*800 + e0];
      acc0 = MFMA16(a0, bf, acc0, 0,0,0);
      acc1 = MFMA16(a1, bf, acc1, 0,0,0);
    }
    #pragma unroll
    for (int r = 0; r < 4; r++){                     // D: row=(l>>4)*4+r, col=l&15
      int rl = kg*4 + r;
      float v0 = (t0 + rl      < L) ? acc0[r] : 0.f;
      float v1 = (t0 + 16 + rl < L) ? acc1[r] : 0.f;
      out[(n0 +      rl)*400 + col] = v0;
      out[(n0 + 16 + rl)*400 + col] = v1;
    }
  }
}

extern "C" void kernel_launch(void* const* d_in, const int* in_sizes, int n_in,
                              void* d_out, int out_size, void* d_ws, size_t ws_size,
                              hipStream_t stream){
  const float* x1   = (const float*)d_in[0];
  const float* x2   = (const float*)d_in[1];
  // d_in[2] = cate: unused by the reference
  const int*   seq  = (const int*)d_in[3];
  const float* wihf = (const float*)d_in[4];
  const float* whhf = (const float*)d_in[5];
  const float* bihf = (const float*)d_in[6];
  const float* bhhf = (const float*)d_in[7];
  const float* wihb = (const float*)d_in[8];
  const float* whhb = (const float*)d_in[9];
  const float* bihb = (const float*)d_in[10];
  const float* bhhb = (const float*)d_in[11];
  const float* wq   = (const float*)d_in[12];
  const float* bq   = (const float*)d_in[13];
  const float* wk   = (const float*)d_in[14];
  const float* bk   = (const float*)d_in[15];
  const float* wmha = (const float*)d_in[16];
  const float* bmha = (const float*)d_in[17];
  const float* wattn= (const float*)d_in[18];
  // d_in[19] = b_attn: cancels in softmax
  const float* wmlp = (const float*)d_in[20];
  const float* bmlp = (const float*)d_in[21];
  float* out = (float*)d_out;

  char* ws = (char*)d_ws;
  u16*  wqb    = (u16*)(ws + 0);              // 320,000 B
  u16*  wkb    = (u16*)(ws + 320000);         // 320,000
  u16*  wihfb  = (u16*)(ws + 640000);         // 640,000
  u16*  wihbb  = (u16*)(ws + 1280000);        // 640,000
  signed char* w8f  = (signed char*)(ws + 1920000);  // 212,992
  signed char* w8b  = (signed char*)(ws + 2132992);  // 212,992
  float* sclf  = (float*)(ws + 2345984);      // 3,200
  float* sclb  = (float*)(ws + 2349184);      // 3,200
  float* bgf   = (float*)(ws + 2352384);      // 3,200
  float* bgb   = (float*)(ws + 2355584);      // 3,200 -> end 2,358,784
  float* pooled= (float*)(ws + 2359296);      // 13,107,200
  float* x2p   = (float*)(ws + 15466496);     // 13,107,200
  u16*  xWf    = (u16*)(ws + 28573696);       // 13,107,200
  u16*  xWb    = (u16*)(ws + 41680896);       // 13,107,200
  float* h_ws  = (float*)(ws + 54788096);     // 13,107,200 -> end 67,895,296
  float* a_ws  = (float*)(ws + 67895296);     // 32,768
  float* amax_ws=(float*)(ws + 67928064);     // 128 -> 67,928,192
  u16*  wmlpb  = (u16*)(ws + 67928192);       // 640,000 -> end ~68.57MB
  float* x1_att= (float*)(ws + 28573696);     // overlay: xWf dead after k41

  k0_cvt  <<<dim3(1250), dim3(256), 0, stream>>>(wq, wk, wihf, wihb, wmlp,
                                                 bihf, bhhf, bihb, bhhb,
                                                 wqb, wkb, wihfb, wihbb, wmlpb, bgf, bgb);
  k0b_quant<<<dim3(416), dim3(256), 0, stream>>>(whhf, whhb, w8f, w8b, sclf, sclb);
  k3_xw   <<<dim3(256),  dim3(512), 0, stream>>>(x1, seq, wihfb, wihbb, bgf, bgb, xWf, xWb);
  k41_fused<<<dim3(2064), dim3(512), 0, stream>>>(xWf, xWb, w8f, w8b, sclf, sclb, seq, h_ws,
                                                  x2, wqb, bq, wkb, bk, pooled);
  k2_x2p  <<<dim3(1024), dim3(256), 0, stream>>>(pooled, wmha, bmha, x2p);
  k4b_fill<<<dim3(32),   dim3(256), 0, stream>>>(seq, h_ws, wattn, a_ws, amax_ws);
  k5_attn <<<dim3(256),  dim3(256), 0, stream>>>(h_ws, a_ws, amax_ws, x1_att);
  k6_out  <<<dim3(256),  dim3(512), 0, stream>>>(x1_att, x2p, wmlpb, bmlp, seq, out);
}